// Round 17
// baseline (819.558 us; speedup 1.0000x reference)
//
#include <hip/hip_runtime.h>

#define T_ 4
#define B_ 16
#define C_ 512
#define N_ 256
#define TB_ 64

using u64 = unsigned long long;
typedef int v4i __attribute__((ext_vector_type(4)));

// ============================ shared helpers ================================

__device__ __forceinline__ void digitize6(float xf, double scale, int d[6]) {
  double m = (double)xf * scale;
  long long t = (long long)rint(m);
#pragma unroll
  for (int s = 5; s >= 0; --s) {
    int dig = (int)((t + 128) & 255) - 128;
    d[s] = dig;
    t = (t - dig) >> 8;
  }
}

__device__ __forceinline__ void digitize5(float xf, double scale, int d[5]) {
  double m = (double)xf * scale;
  long long t = (long long)rint(m);
#pragma unroll
  for (int s = 4; s >= 0; --s) {
    int dig = (int)((t + 128) & 255) - 128;
    d[s] = dig;
    t = (t - dig) >> 8;
  }
}

// 4-digit balanced base-256, S=2^28 (span +-8; exact for |x|>=2^-5 fp32).
__device__ __forceinline__ void dig4(float xv, int d[4]) {
  float c = fminf(fmaxf(xv, -7.999999f), 7.999999f);
  int m = (int)rintf(c * 268435456.0f);
#pragma unroll
  for (int t = 3; t >= 0; --t) {
    int dd = ((m + 128) & 255) - 128;
    d[t] = dd;
    m = (m - dd) >> 8;
  }
}

// async global->LDS, 16B per lane. LDS dest = wave-uniform base + lane*16.
__device__ __forceinline__ void gload16(const void* g, void* l) {
  __builtin_amdgcn_global_load_lds(
      (const __attribute__((address_space(1))) unsigned int*)(unsigned long long)g,
      (__attribute__((address_space(3))) unsigned int*)(unsigned long long)l,
      16, 0, 0);
}

// ===================== STORED-PLANE FAST PATH kernels =======================

// X [TB][C][N] f32 -> Xd4 [tb][n][4t][512c] i8 (transposed, MFMA-ready rows)
__global__ __launch_bounds__(256) void predig_x(
    const float* __restrict__ X, char* __restrict__ Xd4)
{
  const int cb = blockIdx.x * 64;
  const int nb = blockIdx.y * 64;
  const int tb = blockIdx.z;
  const int n  = threadIdx.x & 63;
  const int c0 = (threadIdx.x >> 6) * 16;
  int dg[16][4];
#pragma unroll
  for (int j = 0; j < 16; ++j) {
    float xv = X[((size_t)tb * C_ + cb + c0 + j) * N_ + nb + n];
    dig4(xv, dg[j]);
  }
#pragma unroll
  for (int t = 0; t < 4; ++t) {
    unsigned w[4];
#pragma unroll
    for (int q = 0; q < 4; ++q)
      w[q] = (unsigned)(dg[4*q+0][t] & 255)
           | ((unsigned)(dg[4*q+1][t] & 255) << 8)
           | ((unsigned)(dg[4*q+2][t] & 255) << 16)
           | ((unsigned)(dg[4*q+3][t] & 255) << 24);
    uint4 u; u.x = w[0]; u.y = w[1]; u.z = w[2]; u.w = w[3];
    *reinterpret_cast<uint4*>(
        &Xd4[(((size_t)tb * N_ + nb + n) * 4 + t) * C_ + cb + c0]) = u;
  }
}

// W [o][c] f32 -> Wsl [o][5s][512c] i8 interleaved, scale 2^39.
__global__ __launch_bounds__(128) void decomp_w5i(
    const float* __restrict__ W, char* __restrict__ Wsl)
{
  const int o = blockIdx.x;
  const int k4 = threadIdx.x * 4;
  float4 w4 = *reinterpret_cast<const float4*>(&W[(size_t)o * C_ + k4]);
  int d[4][5];
  digitize5(w4.x, 0x1p39, d[0]);
  digitize5(w4.y, 0x1p39, d[1]);
  digitize5(w4.z, 0x1p39, d[2]);
  digitize5(w4.w, 0x1p39, d[3]);
#pragma unroll
  for (int s = 0; s < 5; ++s) {
    unsigned u = (unsigned)(d[0][s] & 255) | ((unsigned)(d[1][s] & 255) << 8)
               | ((unsigned)(d[2][s] & 255) << 16) | ((unsigned)(d[3][s] & 255) << 24);
    *reinterpret_cast<unsigned*>(&Wsl[((size_t)o * 5 + s) * C_ + k4]) = u;
  }
}

// GEMM on pre-digitized planes — 8-WAVE blocks (512 thr), wave tile 32o x 16n
// (acc 40 regs -> ~110-120 total -> 4 waves/SIMD), same 64x64 block tile and
// R15-proven global_load_lds staging (source-side swizzle, linear LDS dest),
// 2-buffer + __syncthreads. Per-output MFMA chain identical to R10..R16
// (same i,s,t order, same operands) -> bit-identical Y.
// XP=4: B = Xd4 [tb][n][4][512], 14 pairs (s+t<=4), W0 = 2^-11
// XP=1: B = Sp8 [tb][n][512] binary, 5 pairs,        W0 = 2^-7
template<int XP>
__global__ __launch_bounds__(512) void gemm_s(
    const char* __restrict__ Bp, const char* __restrict__ Wsl,
    double* __restrict__ Y)
{
  __shared__ v4i Bls[2][XP][64][4];   // [buf][t][n][16B-slot]
  const int tb = blockIdx.z;
  const int ob = blockIdx.y * 64;
  const int nb = blockIdx.x * 64;
  const int tid = threadIdx.x;
  const int lane = tid & 63;
  const int wv = tid >> 6;          // 0..7
  const int wo = (wv & 1) * 32;     // o-offset
  const int wn = (wv >> 1) * 16;    // n-offset (0,16,32,48)
  const int lr = lane & 15;
  const int lg = lane >> 4;

  v4i acc[5][2] = {};   // [u][ot] — 40 regs

  const char* a0 = Wsl + ((size_t)(ob + wo + lr) * 5) * C_ + lg * 16;
  const char* a1 = a0 + (size_t)16 * 5 * C_;

  // staging geometry: XP=4 -> wave wv covers plane (wv&3), row-half
  // (wv>>2)*32 (2 gload16). XP=1 -> waves 0..3 cover rows wv*16 (1 each).
  const int splane = wv & 3;
  const int srow0  = (wv >> 2) * 32;
  const int s_slot = lane & 3;
  const char* gsrc[(XP == 4) ? 2 : 1];
  if (XP == 4) {
#pragma unroll
    for (int r = 0; r < 2; ++r) {
      int sn = srow0 + r * 16 + (lane >> 2);
      gsrc[r] = Bp + (((size_t)tb * N_ + nb + sn) * 4 + splane) * C_
              + ((s_slot ^ ((sn >> 1) & 3)) * 16);
    }
  } else {
    int sn = (wv & 3) * 16 + (lane >> 2);
    gsrc[0] = Bp + ((size_t)tb * N_ + nb + sn) * C_
            + ((s_slot ^ ((sn >> 1) & 3)) * 16);
  }

#define STAGE_(buf, cb) do {                                              \
    if (XP == 4) {                                                        \
      gload16(gsrc[0] + (cb), &Bls[buf][splane][srow0][0]);               \
      gload16(gsrc[1] + (cb), &Bls[buf][splane][srow0 + 16][0]);          \
    } else {                                                              \
      if (wv < 4) gload16(gsrc[0] + (cb), &Bls[buf][0][(wv & 3) * 16][0]);\
    }                                                                     \
  } while (0)

  // prologue: stage chunk 0 into buf 0
  STAGE_(0, 0);
  __syncthreads();

#pragma unroll
  for (int i = 0; i < 8; ++i) {
    const int cur = i & 1;
    const int cb = i * 64;
    // A loads FIRST (older in vmcnt queue -> pre-MFMA wait leaves staging
    // in flight across the MFMA cluster)
    v4i Af[5][2];
#pragma unroll
    for (int s = 0; s < 5; ++s) {
      Af[s][0] = *reinterpret_cast<const v4i*>(a0 + (size_t)s * C_ + cb);
      Af[s][1] = *reinterpret_cast<const v4i*>(a1 + (size_t)s * C_ + cb);
    }
    __builtin_amdgcn_sched_barrier(0);
    if (i < 7) STAGE_(cur ^ 1, cb + 64);
    __builtin_amdgcn_sched_barrier(0);
    // B fragments from LDS (swizzled read matches source pre-swizzle)
    v4i Bf[XP];
#pragma unroll
    for (int t = 0; t < XP; ++t) {
      const int n = wn + lr;
      Bf[t] = Bls[cur][t][n][lg ^ ((n >> 1) & 3)];
    }
    // MFMA cluster (identical per-output sequence -> bit-identical Y)
#pragma unroll
    for (int s = 0; s < 5; ++s)
#pragma unroll
      for (int t = 0; t < XP; ++t) {
        if (s + t <= 4) {
#pragma unroll
          for (int ot = 0; ot < 2; ++ot)
            acc[s + t][ot] = __builtin_amdgcn_mfma_i32_16x16x64_i8(
                Af[s][ot], Bf[t], acc[s + t][ot], 0, 0, 0);
        }
      }
    if (i < 7) __syncthreads();
  }
#undef STAGE_

  const double W0 = (XP == 4) ? 0x1p-11 : 0x1p-7;
#pragma unroll
  for (int ot = 0; ot < 2; ++ot)
#pragma unroll
    for (int r = 0; r < 4; ++r) {
      double y = 0.0;
      double wgt = W0;
#pragma unroll
      for (int u = 0; u < 5; ++u) {
        y = fma((double)acc[u][ot][r], wgt, y);
        wgt *= 0x1p-8;
      }
      int o = ob + wo + ot * 16 + lg * 4 + r;
      int n = nb + wn + lr;
      Y[((size_t)tb * C_ + o) * N_ + n] = y;
    }
}

// BN stats, split: 4096 blocks (channel x 8 tb-groups) -> partials,
// then one 512-thread block finalizes in fixed order. Deterministic.
__global__ __launch_bounds__(256) void bn_stats_part(
    const double* __restrict__ Y, double* __restrict__ part)
{
  const int ch = blockIdx.x >> 3;
  const int g  = blockIdx.x & 7;
  const int n = threadIdx.x;
  double s = 0.0, s2 = 0.0;
#pragma unroll
  for (int k = 0; k < 8; ++k) {
    int tb = g * 8 + k;
    double v = Y[((size_t)tb * C_ + ch) * N_ + n];
    s += v;
    s2 = fma(v, v, s2);
  }
  __shared__ double rs[256], rq[256];
  rs[n] = s; rq[n] = s2;
  __syncthreads();
  for (int off = 128; off > 0; off >>= 1) {
    if (n < off) { rs[n] += rs[n + off]; rq[n] += rq[n + off]; }
    __syncthreads();
  }
  if (n == 0) {
    part[(size_t)(ch * 8 + g) * 2]     = rs[0];
    part[(size_t)(ch * 8 + g) * 2 + 1] = rq[0];
  }
}

__global__ __launch_bounds__(512) void bn_stats_fin(
    const double* __restrict__ part, double* __restrict__ stats)
{
  const int ch = threadIdx.x;
  double s = 0.0, s2 = 0.0;
#pragma unroll
  for (int g = 0; g < 8; ++g) {
    s  += part[(size_t)(ch * 8 + g) * 2];
    s2 += part[(size_t)(ch * 8 + g) * 2 + 1];
  }
  double mu  = s * (1.0 / 16384.0);
  double var = s2 * (1.0 / 16384.0) - mu * mu;
  stats[ch]      = mu;
  stats[C_ + ch] = 1.0 / sqrt(var + 1e-5);
}

// Attention producing i16 counts (a = 0.125 * count applied later).
__global__ __launch_bounds__(256) void attn16(
    const u64* __restrict__ qb, const u64* __restrict__ kb,
    const u64* __restrict__ vb, short* __restrict__ A16)
{
  __shared__ u64 kw[64][4], vw[64][4], qw[64][4];
  __shared__ int kvs[64][64];
  const int h  = blockIdx.x & 7;
  const int tb = blockIdx.x >> 3;
  const int tid = threadIdx.x;
  {
    int dd = tid >> 2, w = tid & 3;
    size_t base = ((size_t)tb * C_ + h * 64 + dd) * 4 + w;
    kw[dd][w] = kb[base];
    vw[dd][w] = vb[base];
    qw[dd][w] = qb[base];
  }
  __syncthreads();
  {
    int dd = tid >> 2;
    int e0 = (tid & 3) << 4;
    u64 k0 = kw[dd][0], k1 = kw[dd][1], k2 = kw[dd][2], k3 = kw[dd][3];
    for (int e = e0; e < e0 + 16; ++e) {
      int c = __popcll(k0 & vw[e][0]) + __popcll(k1 & vw[e][1])
            + __popcll(k2 & vw[e][2]) + __popcll(k3 & vw[e][3]);
      kvs[dd][e] = c;
    }
  }
  __syncthreads();
  const int n = tid;
  u64 qmask = 0;
  {
    int wsel = n >> 6, sh = n & 63;
#pragma unroll
    for (int dd = 0; dd < 64; ++dd)
      qmask |= ((qw[dd][wsel] >> sh) & 1ull) << dd;
  }
  short* Ap = A16 + ((size_t)tb * C_ + h * 64) * N_ + n;
  for (int e = 0; e < 64; ++e) {
    int s = 0;
#pragma unroll
    for (int dd = 0; dd < 64; ++dd) {
      int m = -(int)((qmask >> dd) & 1ull);
      s += kvs[dd][e] & m;
    }
    Ap[(size_t)e * N_] = (short)s;
  }
}

// attn LIF (vth=0.5, exact fp32 on dyadics) -> binary i8 spikes transposed
// Sp8 [tb][n][512c].
__global__ __launch_bounds__(256) void attn_lif_sp(
    const short* __restrict__ A16, char* __restrict__ Sp8)
{
  const int nb = blockIdx.x * 64;
  const int cb = blockIdx.y * 64;
  const int b  = blockIdx.z;
  const int n  = threadIdx.x & 63;
  const int c0 = (threadIdx.x >> 6) * 16;
  unsigned char sp[4][16];
#pragma unroll
  for (int j = 0; j < 16; ++j) {
    int c = cb + c0 + j;
    float v = 0.f;
#pragma unroll
    for (int t = 0; t < T_; ++t) {
      float a = 0.125f * (float)A16[((size_t)(t * B_ + b) * C_ + c) * N_ + nb + n];
      v = (v + a) * 0.5f;
      bool s = (v >= 0.5f);
      sp[t][j] = s ? 1 : 0;
      if (s) v = 0.f;
    }
  }
#pragma unroll
  for (int t = 0; t < T_; ++t) {
    unsigned w[4];
#pragma unroll
    for (int q = 0; q < 4; ++q)
      w[q] = (unsigned)sp[t][4*q+0] | ((unsigned)sp[t][4*q+1] << 8)
           | ((unsigned)sp[t][4*q+2] << 16) | ((unsigned)sp[t][4*q+3] << 24);
    uint4 u; u.x = w[0]; u.y = w[1]; u.z = w[2]; u.w = w[3];
    *reinterpret_cast<uint4*>(
        &Sp8[((size_t)(t * B_ + b) * N_ + nb + n) * C_ + cb + c0]) = u;
  }
}

// BN-normalize + 4-step LIF, emit bit-packed spikes.
__global__ __launch_bounds__(256) void bn_lif_bits(
    const double* __restrict__ Y, const double* __restrict__ stats,
    const float* __restrict__ gamma, const float* __restrict__ beta,
    double vth, u64* __restrict__ bits)
{
  const int o = blockIdx.x & (C_ - 1);
  const int b = blockIdx.x >> 9;
  const int n = threadIdx.x;
  const double mu = stats[o], rsig = stats[C_ + o];
  const double g = (double)gamma[o], be = (double)beta[o];
  double v = 0.0;
#pragma unroll
  for (int t = 0; t < T_; ++t) {
    double y  = Y[((size_t)(t * B_ + b) * C_ + o) * N_ + n];
    double yn = (y - mu) * rsig * g + be;
    v = v + (yn - v) * 0.5;
    bool sp = (v >= vth);
    u64 m = __ballot(sp);
    if ((n & 63) == 0)
      bits[((size_t)(t * B_ + b) * C_ + o) * (N_ / 64) + (n >> 6)] = m;
    if (sp) v = 0.0;
  }
}

__global__ __launch_bounds__(256) void bn_lif_out(
    const double* __restrict__ Y, const double* __restrict__ stats,
    const float* __restrict__ gamma, const float* __restrict__ beta,
    float* __restrict__ out)
{
  const int o = blockIdx.x & (C_ - 1);
  const int b = blockIdx.x >> 9;
  const int n = threadIdx.x;
  const double mu = stats[o], rsig = stats[C_ + o];
  const double g = (double)gamma[o], be = (double)beta[o];
  double v = 0.0;
#pragma unroll
  for (int t = 0; t < T_; ++t) {
    double y  = Y[((size_t)(t * B_ + b) * C_ + o) * N_ + n];
    double yn = (y - mu) * rsig * g + be;
    v = v + (yn - v) * 0.5;
    bool sp = (v >= 1.0);
    out[((size_t)(t * B_ + b) * C_ + o) * N_ + n] = sp ? 1.0f : 0.0f;
    if (sp) v = 0.0;
  }
}

// ===================== FALLBACK (R4, proven) kernels ========================

__global__ __launch_bounds__(128) void decomp_w(
    const float* __restrict__ W, char* __restrict__ Wsl)
{
  const int o = blockIdx.x;
  const int k4 = threadIdx.x * 4;
  float4 w4 = *reinterpret_cast<const float4*>(&W[(size_t)o * C_ + k4]);
  int d[4][6];
  digitize6(w4.x, 0x1p47, d[0]);
  digitize6(w4.y, 0x1p47, d[1]);
  digitize6(w4.z, 0x1p47, d[2]);
  digitize6(w4.w, 0x1p47, d[3]);
#pragma unroll
  for (int s = 0; s < 6; ++s) {
    unsigned u = (unsigned)(d[0][s] & 255) | ((unsigned)(d[1][s] & 255) << 8)
               | ((unsigned)(d[2][s] & 255) << 16) | ((unsigned)(d[3][s] & 255) << 24);
    *reinterpret_cast<unsigned*>(&Wsl[(size_t)s * C_ * C_ + (size_t)o * C_ + k4]) = u;
  }
}

template<int XS>
__global__ __launch_bounds__(256) void gemm_i8(
    const float* __restrict__ X, const char* __restrict__ Wsl,
    double* __restrict__ Y)
{
  __shared__ char Xs[XS][64][72];
  const int tb = blockIdx.z;
  const int ob = blockIdx.y * 64;
  const int nb = blockIdx.x * 64;
  const int tid = threadIdx.x;
  const int lane = tid & 63;
  const int wv = tid >> 6;
  const int wo = (wv & 1) * 32;
  const int wn = (wv >> 1) * 32;
  const int lr = lane & 15;
  const int lg = lane >> 4;

  constexpr int NU = (XS == 6) ? 7 : 6;
  v4i acc[NU][2][2] = {};

  const int sn = tid & 63;
  const int kq = (tid >> 6) * 4;

  for (int cb = 0; cb < C_; cb += 64) {
    __syncthreads();
#pragma unroll
    for (int st = 0; st < 4; ++st) {
      int k0 = kq + 16 * st;
      int dg[4][6];
#pragma unroll
      for (int j = 0; j < 4; ++j) {
        float xv = X[((size_t)tb * C_ + cb + k0 + j) * N_ + nb + sn];
        digitize6(xv, 0x1p43, dg[j]);
      }
#pragma unroll
      for (int t = 0; t < XS; ++t) {
        unsigned u = (unsigned)(dg[0][t] & 255) | ((unsigned)(dg[1][t] & 255) << 8)
                   | ((unsigned)(dg[2][t] & 255) << 16) | ((unsigned)(dg[3][t] & 255) << 24);
        *reinterpret_cast<unsigned*>(&Xs[t][sn][k0]) = u;
      }
    }
    __syncthreads();

    v4i Bf[XS][2];
#pragma unroll
    for (int t = 0; t < XS; ++t)
#pragma unroll
      for (int nt = 0; nt < 2; ++nt) {
        const char* p = &Xs[t][wn + nt * 16 + lr][lg * 16];
        int2 lo = *reinterpret_cast<const int2*>(p);
        int2 hi = *reinterpret_cast<const int2*>(p + 8);
        v4i b; b[0] = lo.x; b[1] = lo.y; b[2] = hi.x; b[3] = hi.y;
        Bf[t][nt] = b;
      }

#pragma unroll
    for (int s = 0; s < 6; ++s) {
      v4i Af[2];
#pragma unroll
      for (int ot = 0; ot < 2; ++ot) {
        const char* ap = Wsl + (size_t)s * C_ * C_
                       + (size_t)(ob + wo + ot * 16 + lr) * C_ + cb + lg * 16;
        Af[ot] = *reinterpret_cast<const v4i*>(ap);
      }
#pragma unroll
      for (int t = 0; t < XS; ++t) {
        if (s + t <= 6) {
#pragma unroll
          for (int ot = 0; ot < 2; ++ot)
#pragma unroll
            for (int nt = 0; nt < 2; ++nt)
              acc[s + t][ot][nt] = __builtin_amdgcn_mfma_i32_16x16x64_i8(
                  Af[ot], Bf[t][nt], acc[s + t][ot][nt], 0, 0, 0);
        }
      }
    }
  }

  const double WGT[7] = {0x1p-10, 0x1p-18, 0x1p-26, 0x1p-34,
                         0x1p-42, 0x1p-50, 0x1p-58};
#pragma unroll
  for (int ot = 0; ot < 2; ++ot)
#pragma unroll
    for (int nt = 0; nt < 2; ++nt)
#pragma unroll
      for (int r = 0; r < 4; ++r) {
        double y = 0.0;
#pragma unroll
        for (int u = 0; u < NU; ++u)
          y = fma((double)acc[u][ot][nt][r], WGT[u], y);
        int o = ob + wo + ot * 16 + lg * 4 + r;
        int n = nb + wn + nt * 16 + lr;
        Y[((size_t)tb * C_ + o) * N_ + n] = y;
      }
}

__global__ __launch_bounds__(256) void attn_kernel(
    const u64* __restrict__ qb, const u64* __restrict__ kb,
    const u64* __restrict__ vb, float* __restrict__ A)
{
  __shared__ u64 kw[64][4], vw[64][4], qw[64][4];
  __shared__ int kvs[64][64];
  const int h  = blockIdx.x & 7;
  const int tb = blockIdx.x >> 3;
  const int tid = threadIdx.x;
  {
    int dd = tid >> 2, w = tid & 3;
    size_t base = ((size_t)tb * C_ + h * 64 + dd) * 4 + w;
    kw[dd][w] = kb[base];
    vw[dd][w] = vb[base];
    qw[dd][w] = qb[base];
  }
  __syncthreads();
  {
    int dd = tid >> 2;
    int e0 = (tid & 3) << 4;
    u64 k0 = kw[dd][0], k1 = kw[dd][1], k2 = kw[dd][2], k3 = kw[dd][3];
    for (int e = e0; e < e0 + 16; ++e) {
      int c = __popcll(k0 & vw[e][0]) + __popcll(k1 & vw[e][1])
            + __popcll(k2 & vw[e][2]) + __popcll(k3 & vw[e][3]);
      kvs[dd][e] = c;
    }
  }
  __syncthreads();
  const int n = tid;
  u64 qmask = 0;
  {
    int wsel = n >> 6, sh = n & 63;
#pragma unroll
    for (int dd = 0; dd < 64; ++dd)
      qmask |= ((qw[dd][wsel] >> sh) & 1ull) << dd;
  }
  float* Ap = A + ((size_t)tb * C_ + h * 64) * N_ + n;
  for (int e = 0; e < 64; ++e) {
    int s = 0;
#pragma unroll
    for (int dd = 0; dd < 64; ++dd) {
      int m = -(int)((qmask >> dd) & 1ull);
      s += kvs[dd][e] & m;
    }
    Ap[(size_t)e * N_] = (float)s * 0.125f;
  }
}

__global__ __launch_bounds__(256) void attn_lif(float* __restrict__ A)
{
  const size_t i = (size_t)blockIdx.x * 256 + threadIdx.x;
  const size_t stride = (size_t)B_ * C_ * N_;
  float v = 0.f;
#pragma unroll
  for (int t = 0; t < T_; ++t) {
    float a = A[t * stride + i];
    v = v + (a - v) * 0.5f;
    bool sp = (v >= 0.5f);
    A[t * stride + i] = sp ? 1.0f : 0.0f;
    if (sp) v = 0.f;
  }
}

__global__ __launch_bounds__(256) void bn_stats(
    const double* __restrict__ Y, double* __restrict__ stats)
{
  const int o = blockIdx.x;
  const int n = threadIdx.x;
  double s = 0.0, s2 = 0.0;
  for (int tb = 0; tb < TB_; ++tb) {
    double v = Y[((size_t)tb * C_ + o) * N_ + n];
    s += v;
    s2 = fma(v, v, s2);
  }
  __shared__ double rs[256], rq[256];
  rs[n] = s; rq[n] = s2;
  __syncthreads();
  for (int off = 128; off > 0; off >>= 1) {
    if (n < off) { rs[n] += rs[n + off]; rq[n] += rq[n + off]; }
    __syncthreads();
  }
  if (n == 0) {
    double mu  = rs[0] * (1.0 / 16384.0);
    double var = rq[0] * (1.0 / 16384.0) - mu * mu;
    stats[o]      = mu;
    stats[C_ + o] = 1.0 / sqrt(var + 1e-5);
  }
}

// ---------------------------------------------------------------------------
extern "C" void kernel_launch(void* const* d_in, const int* in_sizes, int n_in,
                              void* d_out, int out_size, void* d_ws, size_t ws_size,
                              hipStream_t stream)
{
  const float* x    = (const float*)d_in[0];
  const float* qW   = (const float*)d_in[1];
  const float* qg   = (const float*)d_in[2];
  const float* qbt  = (const float*)d_in[3];
  const float* kW   = (const float*)d_in[4];
  const float* kg   = (const float*)d_in[5];
  const float* kbt  = (const float*)d_in[6];
  const float* vW   = (const float*)d_in[7];
  const float* vg   = (const float*)d_in[8];
  const float* vbt  = (const float*)d_in[9];
  const float* pW   = (const float*)d_in[10];
  // d_in[11] proj_b cancels exactly under BN mean subtraction -> unused
  const float* pg   = (const float*)d_in[12];
  const float* pbt  = (const float*)d_in[13];

  char* ws = (char*)d_ws;
  double* yD    = (double*)ws;                    // 67,108,864 B
  u64*    bitsQ = (u64*)(ws + 100663296);         //  1,048,576 B
  u64*    bitsK = (u64*)(ws + 101711872);         //  1,048,576 B
  u64*    bitsV = (u64*)(ws + 102760448);         //  1,048,576 B
  double* stats = (double*)(ws + 103809024);      //      8,192 B

  if (ws_size >= 105390080ull) {
    // ---------------- fast path: pre-digitized operand planes ----------------
    char*   Xd4  = ws + 67108864;                 // 33,554,432 B (dead after V)
    short*  A16  = (short*)(ws + 67108864);       // 16,777,216 B (after V gemm)
    char*   Sp8  = ws + 67108864 + 16777216;      //  8,388,608 B
    char*   Wsl5 = ws + 103817216;                //  1,310,720 B
    double* part = (double*)(ws + 105127936);     //     65,536 B

    dim3 ggrid(4, 8, 64);

    predig_x<<<dim3(8, 4, 64), 256, 0, stream>>>(x, Xd4);
    // Q
    decomp_w5i<<<512, 128, 0, stream>>>(qW, Wsl5);
    gemm_s<4><<<ggrid, 512, 0, stream>>>(Xd4, Wsl5, yD);
    bn_stats_part<<<4096, 256, 0, stream>>>(yD, part);
    bn_stats_fin<<<1, 512, 0, stream>>>(part, stats);
    bn_lif_bits<<<8192, 256, 0, stream>>>(yD, stats, qg, qbt, 1.0, bitsQ);
    // K
    decomp_w5i<<<512, 128, 0, stream>>>(kW, Wsl5);
    gemm_s<4><<<ggrid, 512, 0, stream>>>(Xd4, Wsl5, yD);
    bn_stats_part<<<4096, 256, 0, stream>>>(yD, part);
    bn_stats_fin<<<1, 512, 0, stream>>>(part, stats);
    bn_lif_bits<<<8192, 256, 0, stream>>>(yD, stats, kg, kbt, 1.0, bitsK);
    // V
    decomp_w5i<<<512, 128, 0, stream>>>(vW, Wsl5);
    gemm_s<4><<<ggrid, 512, 0, stream>>>(Xd4, Wsl5, yD);
    bn_stats_part<<<4096, 256, 0, stream>>>(yD, part);
    bn_stats_fin<<<1, 512, 0, stream>>>(part, stats);
    bn_lif_bits<<<8192, 256, 0, stream>>>(yD, stats, vg, vbt, 1.0, bitsV);
    // attention (exact int) + LIF -> transposed binary i8 (overwrites Xd4)
    attn16<<<512, 256, 0, stream>>>(bitsQ, bitsK, bitsV, A16);
    attn_lif_sp<<<dim3(4, 8, 16), 256, 0, stream>>>(A16, Sp8);
    // projection (binary B, 5 w-digits)
    decomp_w5i<<<512, 128, 0, stream>>>(pW, Wsl5);
    gemm_s<1><<<ggrid, 512, 0, stream>>>(Sp8, Wsl5, yD);
    bn_stats_part<<<4096, 256, 0, stream>>>(yD, part);
    bn_stats_fin<<<1, 512, 0, stream>>>(part, stats);
    bn_lif_out<<<8192, 256, 0, stream>>>(yD, stats, pg, pbt, (float*)d_out);
  } else {
    // ---------------- fallback: proven R4 pipeline ----------------
    float* A    = (float*)(ws + 67108864);
    char*  WslA = ws + 67108864;
    char*  WslB = ws + 100663296;

    dim3 ggrid(4, 8, 64);

    decomp_w<<<512, 128, 0, stream>>>(qW, WslA);
    gemm_i8<6><<<ggrid, 256, 0, stream>>>(x, WslA, yD);
    bn_stats<<<512, 256, 0, stream>>>(yD, stats);
    bn_lif_bits<<<8192, 256, 0, stream>>>(yD, stats, qg, qbt, 1.0, bitsQ);
    decomp_w<<<512, 128, 0, stream>>>(kW, WslA);
    gemm_i8<6><<<ggrid, 256, 0, stream>>>(x, WslA, yD);
    bn_stats<<<512, 256, 0, stream>>>(yD, stats);
    bn_lif_bits<<<8192, 256, 0, stream>>>(yD, stats, kg, kbt, 1.0, bitsK);
    decomp_w<<<512, 128, 0, stream>>>(vW, WslA);
    gemm_i8<6><<<ggrid, 256, 0, stream>>>(x, WslA, yD);
    bn_stats<<<512, 256, 0, stream>>>(yD, stats);
    bn_lif_bits<<<8192, 256, 0, stream>>>(yD, stats, vg, vbt, 1.0, bitsV);
    attn_kernel<<<512, 256, 0, stream>>>(bitsQ, bitsK, bitsV, A);
    attn_lif<<<8192, 256, 0, stream>>>(A);
    decomp_w<<<512, 128, 0, stream>>>(pW, WslB);
    gemm_i8<1><<<ggrid, 256, 0, stream>>>(A, WslB, yD);
    bn_stats<<<512, 256, 0, stream>>>(yD, stats);
    bn_lif_out<<<8192, 256, 0, stream>>>(yD, stats, pg, pbt, (float*)d_out);
  }
}

// Round 18
// 569.543 us; speedup vs baseline: 1.4390x; 1.4390x over previous
//
#include <hip/hip_runtime.h>

#define T_ 4
#define B_ 16
#define C_ 512
#define N_ 256
#define TB_ 64

using u64 = unsigned long long;
typedef int v4i __attribute__((ext_vector_type(4)));

// ============================ shared helpers ================================

__device__ __forceinline__ void digitize6(float xf, double scale, int d[6]) {
  double m = (double)xf * scale;
  long long t = (long long)rint(m);
#pragma unroll
  for (int s = 5; s >= 0; --s) {
    int dig = (int)((t + 128) & 255) - 128;
    d[s] = dig;
    t = (t - dig) >> 8;
  }
}

__device__ __forceinline__ void digitize5(float xf, double scale, int d[5]) {
  double m = (double)xf * scale;
  long long t = (long long)rint(m);
#pragma unroll
  for (int s = 4; s >= 0; --s) {
    int dig = (int)((t + 128) & 255) - 128;
    d[s] = dig;
    t = (t - dig) >> 8;
  }
}

// 4-digit balanced base-256, S=2^28 (span +-8; exact for |x|>=2^-5 fp32).
__device__ __forceinline__ void dig4(float xv, int d[4]) {
  float c = fminf(fmaxf(xv, -7.999999f), 7.999999f);
  int m = (int)rintf(c * 268435456.0f);
#pragma unroll
  for (int t = 3; t >= 0; --t) {
    int dd = ((m + 128) & 255) - 128;
    d[t] = dd;
    m = (m - dd) >> 8;
  }
}

// async global->LDS, 16B per lane. LDS dest = wave-uniform base + lane*16.
__device__ __forceinline__ void gload16(const void* g, void* l) {
  __builtin_amdgcn_global_load_lds(
      (const __attribute__((address_space(1))) unsigned int*)(unsigned long long)g,
      (__attribute__((address_space(3))) unsigned int*)(unsigned long long)l,
      16, 0, 0);
}

// ===================== STORED-PLANE FAST PATH kernels =======================

// X [TB][C][N] f32 -> Xd4 [tb][n][4t][512c] i8 (transposed, MFMA-ready rows)
__global__ __launch_bounds__(256) void predig_x(
    const float* __restrict__ X, char* __restrict__ Xd4)
{
  const int cb = blockIdx.x * 64;
  const int nb = blockIdx.y * 64;
  const int tb = blockIdx.z;
  const int n  = threadIdx.x & 63;
  const int c0 = (threadIdx.x >> 6) * 16;
  int dg[16][4];
#pragma unroll
  for (int j = 0; j < 16; ++j) {
    float xv = X[((size_t)tb * C_ + cb + c0 + j) * N_ + nb + n];
    dig4(xv, dg[j]);
  }
#pragma unroll
  for (int t = 0; t < 4; ++t) {
    unsigned w[4];
#pragma unroll
    for (int q = 0; q < 4; ++q)
      w[q] = (unsigned)(dg[4*q+0][t] & 255)
           | ((unsigned)(dg[4*q+1][t] & 255) << 8)
           | ((unsigned)(dg[4*q+2][t] & 255) << 16)
           | ((unsigned)(dg[4*q+3][t] & 255) << 24);
    uint4 u; u.x = w[0]; u.y = w[1]; u.z = w[2]; u.w = w[3];
    *reinterpret_cast<uint4*>(
        &Xd4[(((size_t)tb * N_ + nb + n) * 4 + t) * C_ + cb + c0]) = u;
  }
}

// W [o][c] f32 -> Wsl [o][5s][512c] i8 interleaved, scale 2^39.
__global__ __launch_bounds__(128) void decomp_w5i(
    const float* __restrict__ W, char* __restrict__ Wsl)
{
  const int o = blockIdx.x;
  const int k4 = threadIdx.x * 4;
  float4 w4 = *reinterpret_cast<const float4*>(&W[(size_t)o * C_ + k4]);
  int d[4][5];
  digitize5(w4.x, 0x1p39, d[0]);
  digitize5(w4.y, 0x1p39, d[1]);
  digitize5(w4.z, 0x1p39, d[2]);
  digitize5(w4.w, 0x1p39, d[3]);
#pragma unroll
  for (int s = 0; s < 5; ++s) {
    unsigned u = (unsigned)(d[0][s] & 255) | ((unsigned)(d[1][s] & 255) << 8)
               | ((unsigned)(d[2][s] & 255) << 16) | ((unsigned)(d[3][s] & 255) << 24);
    *reinterpret_cast<unsigned*>(&Wsl[((size_t)o * 5 + s) * C_ + k4]) = u;
  }
}

// GEMM on pre-digitized planes — R15-proven structure (global_load_lds
// staging, source-side swizzle, linear LDS dest, 2-buffer + __syncthreads,
// 4 waves, 64x64 tile) + XCD-AWARE 1-D GRID SWIZZLE: linear id =
// (tb*4 + nb) + 256*ob, so the 8 ob-blocks sharing one (nb,tb) Xd4 slice
// have ids congruent mod 8 -> land on the SAME XCD (id%8 dispatch) -> the
// 128KB slice is fetched into one L2 instead of eight. Performance-only;
// per-output MFMA chain identical to R10..R16 -> bit-identical Y.
// XP=4: B = Xd4 [tb][n][4][512], 14 pairs (s+t<=4), W0 = 2^-11
// XP=1: B = Sp8 [tb][n][512] binary, 5 pairs,        W0 = 2^-7
template<int XP>
__global__ __launch_bounds__(256) void gemm_s(
    const char* __restrict__ Bp, const char* __restrict__ Wsl,
    double* __restrict__ Y)
{
  __shared__ v4i Bls[2][XP][64][4];   // [buf][t][n][16B-slot]
  const int id  = blockIdx.x;
  const int ob  = (id >> 8) * 64;       // 0..7 -> o-tile
  const int low = id & 255;
  const int tb  = low >> 2;             // 0..63
  const int nb  = (low & 3) * 64;       // 0..3 -> n-tile
  const int tid = threadIdx.x;
  const int lane = tid & 63;
  const int wv = tid >> 6;
  const int wo = (wv & 1) * 32;
  const int wn = (wv >> 1) * 32;
  const int lr = lane & 15;
  const int lg = lane >> 4;

  v4i acc[5][2][2] = {};

  const char* a0 = Wsl + ((size_t)(ob + wo + lr) * 5) * C_ + lg * 16;
  const char* a1 = a0 + (size_t)16 * 5 * C_;

  // staging geometry: wave wv covers plane wv (XP=4) / row-group wv (XP=1).
  const int s_slot = lane & 3;
  const char* gsrc[(XP == 4) ? 4 : 1];
  if (XP == 4) {
#pragma unroll
    for (int r = 0; r < 4; ++r) {
      int sn = r * 16 + (lane >> 2);
      gsrc[r] = Bp + (((size_t)tb * N_ + nb + sn) * 4 + wv) * C_
              + ((s_slot ^ ((sn >> 1) & 3)) * 16);
    }
  } else {
    int sn = wv * 16 + (lane >> 2);
    gsrc[0] = Bp + ((size_t)tb * N_ + nb + sn) * C_
            + ((s_slot ^ ((sn >> 1) & 3)) * 16);
  }

#define STAGE_(buf, cb) do {                                              \
    if (XP == 4) {                                                        \
      _Pragma("unroll")                                                   \
      for (int r_ = 0; r_ < 4; ++r_)                                      \
        gload16(gsrc[r_] + (cb), &Bls[buf][wv][r_ * 16][0]);              \
    } else {                                                              \
      gload16(gsrc[0] + (cb), &Bls[buf][0][wv * 16][0]);                  \
    }                                                                     \
  } while (0)

  // prologue: stage chunk 0 into buf 0
  STAGE_(0, 0);
  __syncthreads();

#pragma unroll
  for (int i = 0; i < 8; ++i) {
    const int cur = i & 1;
    const int cb = i * 64;
    // A loads FIRST (older in vmcnt queue -> pre-MFMA wait leaves staging
    // in flight)
    v4i Af[5][2];
#pragma unroll
    for (int s = 0; s < 5; ++s) {
      Af[s][0] = *reinterpret_cast<const v4i*>(a0 + (size_t)s * C_ + cb);
      Af[s][1] = *reinterpret_cast<const v4i*>(a1 + (size_t)s * C_ + cb);
    }
    __builtin_amdgcn_sched_barrier(0);
    if (i < 7) STAGE_(cur ^ 1, cb + 64);
    __builtin_amdgcn_sched_barrier(0);
    // B fragments from LDS (swizzled read matches source pre-swizzle)
    v4i Bf[XP][2];
#pragma unroll
    for (int t = 0; t < XP; ++t)
#pragma unroll
      for (int nt = 0; nt < 2; ++nt) {
        const int n = wn + nt * 16 + lr;
        Bf[t][nt] = Bls[cur][t][n][lg ^ ((n >> 1) & 3)];
      }
    // MFMA cluster (identical sequence/order -> bit-identical output)
#pragma unroll
    for (int s = 0; s < 5; ++s)
#pragma unroll
      for (int t = 0; t < XP; ++t) {
        if (s + t <= 4) {
#pragma unroll
          for (int ot = 0; ot < 2; ++ot)
#pragma unroll
            for (int nt = 0; nt < 2; ++nt)
              acc[s + t][ot][nt] = __builtin_amdgcn_mfma_i32_16x16x64_i8(
                  Af[s][ot], Bf[t][nt], acc[s + t][ot][nt], 0, 0, 0);
        }
      }
    if (i < 7) __syncthreads();
  }
#undef STAGE_

  const double W0 = (XP == 4) ? 0x1p-11 : 0x1p-7;
#pragma unroll
  for (int ot = 0; ot < 2; ++ot)
#pragma unroll
    for (int nt = 0; nt < 2; ++nt)
#pragma unroll
      for (int r = 0; r < 4; ++r) {
        double y = 0.0;
        double wgt = W0;
#pragma unroll
        for (int u = 0; u < 5; ++u) {
          y = fma((double)acc[u][ot][nt][r], wgt, y);
          wgt *= 0x1p-8;
        }
        int o = ob + wo + ot * 16 + lg * 4 + r;
        int n = nb + wn + nt * 16 + lr;
        Y[((size_t)tb * C_ + o) * N_ + n] = y;
      }
}

// BN stats partials: 4096 blocks (channel x 8 tb-groups). Deterministic.
__global__ __launch_bounds__(256) void bn_stats_part(
    const double* __restrict__ Y, double* __restrict__ part)
{
  const int ch = blockIdx.x >> 3;
  const int g  = blockIdx.x & 7;
  const int n = threadIdx.x;
  double s = 0.0, s2 = 0.0;
#pragma unroll
  for (int k = 0; k < 8; ++k) {
    int tb = g * 8 + k;
    double v = Y[((size_t)tb * C_ + ch) * N_ + n];
    s += v;
    s2 = fma(v, v, s2);
  }
  __shared__ double rs[256], rq[256];
  rs[n] = s; rq[n] = s2;
  __syncthreads();
  for (int off = 128; off > 0; off >>= 1) {
    if (n < off) { rs[n] += rs[n + off]; rq[n] += rq[n + off]; }
    __syncthreads();
  }
  if (n == 0) {
    part[(size_t)(ch * 8 + g) * 2]     = rs[0];
    part[(size_t)(ch * 8 + g) * 2 + 1] = rq[0];
  }
}

// finalize stats inline (identical fixed g-order to the old bn_stats_fin)
__device__ __forceinline__ void stats_from_part(
    const double* __restrict__ part, int ch, double& mu, double& rsig)
{
  double s = 0.0, s2 = 0.0;
#pragma unroll
  for (int g = 0; g < 8; ++g) {
    s  += part[(size_t)(ch * 8 + g) * 2];
    s2 += part[(size_t)(ch * 8 + g) * 2 + 1];
  }
  mu = s * (1.0 / 16384.0);
  double var = s2 * (1.0 / 16384.0) - mu * mu;
  rsig = 1.0 / sqrt(var + 1e-5);
}

// Attention producing i16 counts (a = 0.125 * count applied later).
__global__ __launch_bounds__(256) void attn16(
    const u64* __restrict__ qb, const u64* __restrict__ kb,
    const u64* __restrict__ vb, short* __restrict__ A16)
{
  __shared__ u64 kw[64][4], vw[64][4], qw[64][4];
  __shared__ int kvs[64][64];
  const int h  = blockIdx.x & 7;
  const int tb = blockIdx.x >> 3;
  const int tid = threadIdx.x;
  {
    int dd = tid >> 2, w = tid & 3;
    size_t base = ((size_t)tb * C_ + h * 64 + dd) * 4 + w;
    kw[dd][w] = kb[base];
    vw[dd][w] = vb[base];
    qw[dd][w] = qb[base];
  }
  __syncthreads();
  {
    int dd = tid >> 2;
    int e0 = (tid & 3) << 4;
    u64 k0 = kw[dd][0], k1 = kw[dd][1], k2 = kw[dd][2], k3 = kw[dd][3];
    for (int e = e0; e < e0 + 16; ++e) {
      int c = __popcll(k0 & vw[e][0]) + __popcll(k1 & vw[e][1])
            + __popcll(k2 & vw[e][2]) + __popcll(k3 & vw[e][3]);
      kvs[dd][e] = c;
    }
  }
  __syncthreads();
  const int n = tid;
  u64 qmask = 0;
  {
    int wsel = n >> 6, sh = n & 63;
#pragma unroll
    for (int dd = 0; dd < 64; ++dd)
      qmask |= ((qw[dd][wsel] >> sh) & 1ull) << dd;
  }
  short* Ap = A16 + ((size_t)tb * C_ + h * 64) * N_ + n;
  for (int e = 0; e < 64; ++e) {
    int s = 0;
#pragma unroll
    for (int dd = 0; dd < 64; ++dd) {
      int m = -(int)((qmask >> dd) & 1ull);
      s += kvs[dd][e] & m;
    }
    Ap[(size_t)e * N_] = (short)s;
  }
}

// attn LIF (vth=0.5, exact fp32 on dyadics) -> binary i8 spikes transposed
// Sp8 [tb][n][512c].
__global__ __launch_bounds__(256) void attn_lif_sp(
    const short* __restrict__ A16, char* __restrict__ Sp8)
{
  const int nb = blockIdx.x * 64;
  const int cb = blockIdx.y * 64;
  const int b  = blockIdx.z;
  const int n  = threadIdx.x & 63;
  const int c0 = (threadIdx.x >> 6) * 16;
  unsigned char sp[4][16];
#pragma unroll
  for (int j = 0; j < 16; ++j) {
    int c = cb + c0 + j;
    float v = 0.f;
#pragma unroll
    for (int t = 0; t < T_; ++t) {
      float a = 0.125f * (float)A16[((size_t)(t * B_ + b) * C_ + c) * N_ + nb + n];
      v = (v + a) * 0.5f;
      bool s = (v >= 0.5f);
      sp[t][j] = s ? 1 : 0;
      if (s) v = 0.f;
    }
  }
#pragma unroll
  for (int t = 0; t < T_; ++t) {
    unsigned w[4];
#pragma unroll
    for (int q = 0; q < 4; ++q)
      w[q] = (unsigned)sp[t][4*q+0] | ((unsigned)sp[t][4*q+1] << 8)
           | ((unsigned)sp[t][4*q+2] << 16) | ((unsigned)sp[t][4*q+3] << 24);
    uint4 u; u.x = w[0]; u.y = w[1]; u.z = w[2]; u.w = w[3];
    *reinterpret_cast<uint4*>(
        &Sp8[((size_t)(t * B_ + b) * N_ + nb + n) * C_ + cb + c0]) = u;
  }
}

// BN-normalize + 4-step LIF (stats finalized inline from partials).
__global__ __launch_bounds__(256) void bn_lif_bits(
    const double* __restrict__ Y, const double* __restrict__ part,
    const float* __restrict__ gamma, const float* __restrict__ beta,
    double vth, u64* __restrict__ bits)
{
  const int o = blockIdx.x & (C_ - 1);
  const int b = blockIdx.x >> 9;
  const int n = threadIdx.x;
  double mu, rsig;
  stats_from_part(part, o, mu, rsig);
  const double g = (double)gamma[o], be = (double)beta[o];
  double v = 0.0;
#pragma unroll
  for (int t = 0; t < T_; ++t) {
    double y  = Y[((size_t)(t * B_ + b) * C_ + o) * N_ + n];
    double yn = (y - mu) * rsig * g + be;
    v = v + (yn - v) * 0.5;
    bool sp = (v >= vth);
    u64 m = __ballot(sp);
    if ((n & 63) == 0)
      bits[((size_t)(t * B_ + b) * C_ + o) * (N_ / 64) + (n >> 6)] = m;
    if (sp) v = 0.0;
  }
}

__global__ __launch_bounds__(256) void bn_lif_out(
    const double* __restrict__ Y, const double* __restrict__ part,
    const float* __restrict__ gamma, const float* __restrict__ beta,
    float* __restrict__ out)
{
  const int o = blockIdx.x & (C_ - 1);
  const int b = blockIdx.x >> 9;
  const int n = threadIdx.x;
  double mu, rsig;
  stats_from_part(part, o, mu, rsig);
  const double g = (double)gamma[o], be = (double)beta[o];
  double v = 0.0;
#pragma unroll
  for (int t = 0; t < T_; ++t) {
    double y  = Y[((size_t)(t * B_ + b) * C_ + o) * N_ + n];
    double yn = (y - mu) * rsig * g + be;
    v = v + (yn - v) * 0.5;
    bool sp = (v >= 1.0);
    out[((size_t)(t * B_ + b) * C_ + o) * N_ + n] = sp ? 1.0f : 0.0f;
    if (sp) v = 0.0;
  }
}

// ===================== FALLBACK (R4, proven) kernels ========================

__global__ __launch_bounds__(128) void decomp_w(
    const float* __restrict__ W, char* __restrict__ Wsl)
{
  const int o = blockIdx.x;
  const int k4 = threadIdx.x * 4;
  float4 w4 = *reinterpret_cast<const float4*>(&W[(size_t)o * C_ + k4]);
  int d[4][6];
  digitize6(w4.x, 0x1p47, d[0]);
  digitize6(w4.y, 0x1p47, d[1]);
  digitize6(w4.z, 0x1p47, d[2]);
  digitize6(w4.w, 0x1p47, d[3]);
#pragma unroll
  for (int s = 0; s < 6; ++s) {
    unsigned u = (unsigned)(d[0][s] & 255) | ((unsigned)(d[1][s] & 255) << 8)
               | ((unsigned)(d[2][s] & 255) << 16) | ((unsigned)(d[3][s] & 255) << 24);
    *reinterpret_cast<unsigned*>(&Wsl[(size_t)s * C_ * C_ + (size_t)o * C_ + k4]) = u;
  }
}

template<int XS>
__global__ __launch_bounds__(256) void gemm_i8(
    const float* __restrict__ X, const char* __restrict__ Wsl,
    double* __restrict__ Y)
{
  __shared__ char Xs[XS][64][72];
  const int tb = blockIdx.z;
  const int ob = blockIdx.y * 64;
  const int nb = blockIdx.x * 64;
  const int tid = threadIdx.x;
  const int lane = tid & 63;
  const int wv = tid >> 6;
  const int wo = (wv & 1) * 32;
  const int wn = (wv >> 1) * 32;
  const int lr = lane & 15;
  const int lg = lane >> 4;

  constexpr int NU = (XS == 6) ? 7 : 6;
  v4i acc[NU][2][2] = {};

  const int sn = tid & 63;
  const int kq = (tid >> 6) * 4;

  for (int cb = 0; cb < C_; cb += 64) {
    __syncthreads();
#pragma unroll
    for (int st = 0; st < 4; ++st) {
      int k0 = kq + 16 * st;
      int dg[4][6];
#pragma unroll
      for (int j = 0; j < 4; ++j) {
        float xv = X[((size_t)tb * C_ + cb + k0 + j) * N_ + nb + sn];
        digitize6(xv, 0x1p43, dg[j]);
      }
#pragma unroll
      for (int t = 0; t < XS; ++t) {
        unsigned u = (unsigned)(dg[0][t] & 255) | ((unsigned)(dg[1][t] & 255) << 8)
                   | ((unsigned)(dg[2][t] & 255) << 16) | ((unsigned)(dg[3][t] & 255) << 24);
        *reinterpret_cast<unsigned*>(&Xs[t][sn][k0]) = u;
      }
    }
    __syncthreads();

    v4i Bf[XS][2];
#pragma unroll
    for (int t = 0; t < XS; ++t)
#pragma unroll
      for (int nt = 0; nt < 2; ++nt) {
        const char* p = &Xs[t][wn + nt * 16 + lr][lg * 16];
        int2 lo = *reinterpret_cast<const int2*>(p);
        int2 hi = *reinterpret_cast<const int2*>(p + 8);
        v4i b; b[0] = lo.x; b[1] = lo.y; b[2] = hi.x; b[3] = hi.y;
        Bf[t][nt] = b;
      }

#pragma unroll
    for (int s = 0; s < 6; ++s) {
      v4i Af[2];
#pragma unroll
      for (int ot = 0; ot < 2; ++ot) {
        const char* ap = Wsl + (size_t)s * C_ * C_
                       + (size_t)(ob + wo + ot * 16 + lr) * C_ + cb + lg * 16;
        Af[ot] = *reinterpret_cast<const v4i*>(ap);
      }
#pragma unroll
      for (int t = 0; t < XS; ++t) {
        if (s + t <= 6) {
#pragma unroll
          for (int ot = 0; ot < 2; ++ot)
#pragma unroll
            for (int nt = 0; nt < 2; ++nt)
              acc[s + t][ot][nt] = __builtin_amdgcn_mfma_i32_16x16x64_i8(
                  Af[ot], Bf[t][nt], acc[s + t][ot][nt], 0, 0, 0);
        }
      }
    }
  }

  const double WGT[7] = {0x1p-10, 0x1p-18, 0x1p-26, 0x1p-34,
                         0x1p-42, 0x1p-50, 0x1p-58};
#pragma unroll
  for (int ot = 0; ot < 2; ++ot)
#pragma unroll
    for (int nt = 0; nt < 2; ++nt)
#pragma unroll
      for (int r = 0; r < 4; ++r) {
        double y = 0.0;
#pragma unroll
        for (int u = 0; u < NU; ++u)
          y = fma((double)acc[u][ot][nt][r], WGT[u], y);
        int o = ob + wo + ot * 16 + lg * 4 + r;
        int n = nb + wn + nt * 16 + lr;
        Y[((size_t)tb * C_ + o) * N_ + n] = y;
      }
}

__global__ __launch_bounds__(256) void attn_kernel(
    const u64* __restrict__ qb, const u64* __restrict__ kb,
    const u64* __restrict__ vb, float* __restrict__ A)
{
  __shared__ u64 kw[64][4], vw[64][4], qw[64][4];
  __shared__ int kvs[64][64];
  const int h  = blockIdx.x & 7;
  const int tb = blockIdx.x >> 3;
  const int tid = threadIdx.x;
  {
    int dd = tid >> 2, w = tid & 3;
    size_t base = ((size_t)tb * C_ + h * 64 + dd) * 4 + w;
    kw[dd][w] = kb[base];
    vw[dd][w] = vb[base];
    qw[dd][w] = qb[base];
  }
  __syncthreads();
  {
    int dd = tid >> 2;
    int e0 = (tid & 3) << 4;
    u64 k0 = kw[dd][0], k1 = kw[dd][1], k2 = kw[dd][2], k3 = kw[dd][3];
    for (int e = e0; e < e0 + 16; ++e) {
      int c = __popcll(k0 & vw[e][0]) + __popcll(k1 & vw[e][1])
            + __popcll(k2 & vw[e][2]) + __popcll(k3 & vw[e][3]);
      kvs[dd][e] = c;
    }
  }
  __syncthreads();
  const int n = tid;
  u64 qmask = 0;
  {
    int wsel = n >> 6, sh = n & 63;
#pragma unroll
    for (int dd = 0; dd < 64; ++dd)
      qmask |= ((qw[dd][wsel] >> sh) & 1ull) << dd;
  }
  float* Ap = A + ((size_t)tb * C_ + h * 64) * N_ + n;
  for (int e = 0; e < 64; ++e) {
    int s = 0;
#pragma unroll
    for (int dd = 0; dd < 64; ++dd) {
      int m = -(int)((qmask >> dd) & 1ull);
      s += kvs[dd][e] & m;
    }
    Ap[(size_t)e * N_] = (float)s * 0.125f;
  }
}

__global__ __launch_bounds__(256) void attn_lif(float* __restrict__ A)
{
  const size_t i = (size_t)blockIdx.x * 256 + threadIdx.x;
  const size_t stride = (size_t)B_ * C_ * N_;
  float v = 0.f;
#pragma unroll
  for (int t = 0; t < T_; ++t) {
    float a = A[t * stride + i];
    v = v + (a - v) * 0.5f;
    bool sp = (v >= 0.5f);
    A[t * stride + i] = sp ? 1.0f : 0.0f;
    if (sp) v = 0.f;
  }
}

__global__ __launch_bounds__(256) void bn_stats(
    const double* __restrict__ Y, double* __restrict__ stats)
{
  const int o = blockIdx.x;
  const int n = threadIdx.x;
  double s = 0.0, s2 = 0.0;
  for (int tb = 0; tb < TB_; ++tb) {
    double v = Y[((size_t)tb * C_ + o) * N_ + n];
    s += v;
    s2 = fma(v, v, s2);
  }
  __shared__ double rs[256], rq[256];
  rs[n] = s; rq[n] = s2;
  __syncthreads();
  for (int off = 128; off > 0; off >>= 1) {
    if (n < off) { rs[n] += rs[n + off]; rq[n] += rq[n + off]; }
    __syncthreads();
  }
  if (n == 0) {
    double mu  = rs[0] * (1.0 / 16384.0);
    double var = rq[0] * (1.0 / 16384.0) - mu * mu;
    stats[o]      = mu;
    stats[C_ + o] = 1.0 / sqrt(var + 1e-5);
  }
}

__global__ __launch_bounds__(256) void bn_lif_bits_fb(
    const double* __restrict__ Y, const double* __restrict__ stats,
    const float* __restrict__ gamma, const float* __restrict__ beta,
    double vth, u64* __restrict__ bits)
{
  const int o = blockIdx.x & (C_ - 1);
  const int b = blockIdx.x >> 9;
  const int n = threadIdx.x;
  const double mu = stats[o], rsig = stats[C_ + o];
  const double g = (double)gamma[o], be = (double)beta[o];
  double v = 0.0;
#pragma unroll
  for (int t = 0; t < T_; ++t) {
    double y  = Y[((size_t)(t * B_ + b) * C_ + o) * N_ + n];
    double yn = (y - mu) * rsig * g + be;
    v = v + (yn - v) * 0.5;
    bool sp = (v >= vth);
    u64 m = __ballot(sp);
    if ((n & 63) == 0)
      bits[((size_t)(t * B_ + b) * C_ + o) * (N_ / 64) + (n >> 6)] = m;
    if (sp) v = 0.0;
  }
}

__global__ __launch_bounds__(256) void bn_lif_out_fb(
    const double* __restrict__ Y, const double* __restrict__ stats,
    const float* __restrict__ gamma, const float* __restrict__ beta,
    float* __restrict__ out)
{
  const int o = blockIdx.x & (C_ - 1);
  const int b = blockIdx.x >> 9;
  const int n = threadIdx.x;
  const double mu = stats[o], rsig = stats[C_ + o];
  const double g = (double)gamma[o], be = (double)beta[o];
  double v = 0.0;
#pragma unroll
  for (int t = 0; t < T_; ++t) {
    double y  = Y[((size_t)(t * B_ + b) * C_ + o) * N_ + n];
    double yn = (y - mu) * rsig * g + be;
    v = v + (yn - v) * 0.5;
    bool sp = (v >= 1.0);
    out[((size_t)(t * B_ + b) * C_ + o) * N_ + n] = sp ? 1.0f : 0.0f;
    if (sp) v = 0.0;
  }
}

// ---------------------------------------------------------------------------
extern "C" void kernel_launch(void* const* d_in, const int* in_sizes, int n_in,
                              void* d_out, int out_size, void* d_ws, size_t ws_size,
                              hipStream_t stream)
{
  const float* x    = (const float*)d_in[0];
  const float* qW   = (const float*)d_in[1];
  const float* qg   = (const float*)d_in[2];
  const float* qbt  = (const float*)d_in[3];
  const float* kW   = (const float*)d_in[4];
  const float* kg   = (const float*)d_in[5];
  const float* kbt  = (const float*)d_in[6];
  const float* vW   = (const float*)d_in[7];
  const float* vg   = (const float*)d_in[8];
  const float* vbt  = (const float*)d_in[9];
  const float* pW   = (const float*)d_in[10];
  // d_in[11] proj_b cancels exactly under BN mean subtraction -> unused
  const float* pg   = (const float*)d_in[12];
  const float* pbt  = (const float*)d_in[13];

  char* ws = (char*)d_ws;
  double* yD    = (double*)ws;                    // 67,108,864 B
  u64*    bitsQ = (u64*)(ws + 100663296);         //  1,048,576 B
  u64*    bitsK = (u64*)(ws + 101711872);         //  1,048,576 B
  u64*    bitsV = (u64*)(ws + 102760448);         //  1,048,576 B
  double* stats = (double*)(ws + 103809024);      //      8,192 B

  if (ws_size >= 105390080ull) {
    // ---------------- fast path: pre-digitized operand planes ----------------
    char*   Xd4  = ws + 67108864;                 // 33,554,432 B (dead after V)
    short*  A16  = (short*)(ws + 67108864);       // 16,777,216 B (after V gemm)
    char*   Sp8  = ws + 67108864 + 16777216;      //  8,388,608 B
    char*   Wsl5 = ws + 103817216;                //  1,310,720 B
    double* part = (double*)(ws + 105127936);     //     65,536 B

    predig_x<<<dim3(8, 4, 64), 256, 0, stream>>>(x, Xd4);
    // Q
    decomp_w5i<<<512, 128, 0, stream>>>(qW, Wsl5);
    gemm_s<4><<<2048, 256, 0, stream>>>(Xd4, Wsl5, yD);
    bn_stats_part<<<4096, 256, 0, stream>>>(yD, part);
    bn_lif_bits<<<8192, 256, 0, stream>>>(yD, part, qg, qbt, 1.0, bitsQ);
    // K
    decomp_w5i<<<512, 128, 0, stream>>>(kW, Wsl5);
    gemm_s<4><<<2048, 256, 0, stream>>>(Xd4, Wsl5, yD);
    bn_stats_part<<<4096, 256, 0, stream>>>(yD, part);
    bn_lif_bits<<<8192, 256, 0, stream>>>(yD, part, kg, kbt, 1.0, bitsK);
    // V
    decomp_w5i<<<512, 128, 0, stream>>>(vW, Wsl5);
    gemm_s<4><<<2048, 256, 0, stream>>>(Xd4, Wsl5, yD);
    bn_stats_part<<<4096, 256, 0, stream>>>(yD, part);
    bn_lif_bits<<<8192, 256, 0, stream>>>(yD, part, vg, vbt, 1.0, bitsV);
    // attention (exact int) + LIF -> transposed binary i8 (overwrites Xd4)
    attn16<<<512, 256, 0, stream>>>(bitsQ, bitsK, bitsV, A16);
    attn_lif_sp<<<dim3(4, 8, 16), 256, 0, stream>>>(A16, Sp8);
    // projection (binary B, 5 w-digits)
    decomp_w5i<<<512, 128, 0, stream>>>(pW, Wsl5);
    gemm_s<1><<<2048, 256, 0, stream>>>(Sp8, Wsl5, yD);
    bn_stats_part<<<4096, 256, 0, stream>>>(yD, part);
    bn_lif_out<<<8192, 256, 0, stream>>>(yD, part, pg, pbt, (float*)d_out);
  } else {
    // ---------------- fallback: proven R4 pipeline ----------------
    float* A    = (float*)(ws + 67108864);
    char*  WslA = ws + 67108864;
    char*  WslB = ws + 100663296;

    dim3 ggrid(4, 8, 64);

    decomp_w<<<512, 128, 0, stream>>>(qW, WslA);
    gemm_i8<6><<<ggrid, 256, 0, stream>>>(x, WslA, yD);
    bn_stats<<<512, 256, 0, stream>>>(yD, stats);
    bn_lif_bits_fb<<<8192, 256, 0, stream>>>(yD, stats, qg, qbt, 1.0, bitsQ);
    decomp_w<<<512, 128, 0, stream>>>(kW, WslA);
    gemm_i8<6><<<ggrid, 256, 0, stream>>>(x, WslA, yD);
    bn_stats<<<512, 256, 0, stream>>>(yD, stats);
    bn_lif_bits_fb<<<8192, 256, 0, stream>>>(yD, stats, kg, kbt, 1.0, bitsK);
    decomp_w<<<512, 128, 0, stream>>>(vW, WslA);
    gemm_i8<6><<<ggrid, 256, 0, stream>>>(x, WslA, yD);
    bn_stats<<<512, 256, 0, stream>>>(yD, stats);
    bn_lif_bits_fb<<<8192, 256, 0, stream>>>(yD, stats, vg, vbt, 1.0, bitsV);
    attn_kernel<<<512, 256, 0, stream>>>(bitsQ, bitsK, bitsV, A);
    attn_lif<<<8192, 256, 0, stream>>>(A);
    decomp_w<<<512, 128, 0, stream>>>(pW, WslB);
    gemm_i8<1><<<ggrid, 256, 0, stream>>>(A, WslB, yD);
    bn_stats<<<512, 256, 0, stream>>>(yD, stats);
    bn_lif_out_fb<<<8192, 256, 0, stream>>>(yD, stats, pg, pbt, (float*)d_out);
  }
}

// Round 19
// 432.123 us; speedup vs baseline: 1.8966x; 1.3180x over previous
//
#include <hip/hip_runtime.h>

#define T_ 4
#define B_ 16
#define C_ 512
#define N_ 256
#define TB_ 64

using u64 = unsigned long long;
typedef int v4i __attribute__((ext_vector_type(4)));

// ============================ shared helpers ================================

__device__ __forceinline__ void digitize6(float xf, double scale, int d[6]) {
  double m = (double)xf * scale;
  long long t = (long long)rint(m);
#pragma unroll
  for (int s = 5; s >= 0; --s) {
    int dig = (int)((t + 128) & 255) - 128;
    d[s] = dig;
    t = (t - dig) >> 8;
  }
}

__device__ __forceinline__ void digitize5(float xf, double scale, int d[5]) {
  double m = (double)xf * scale;
  long long t = (long long)rint(m);
#pragma unroll
  for (int s = 4; s >= 0; --s) {
    int dig = (int)((t + 128) & 255) - 128;
    d[s] = dig;
    t = (t - dig) >> 8;
  }
}

// 4-digit balanced base-256, S=2^28 (span +-8; exact for |x|>=2^-5 fp32).
__device__ __forceinline__ void dig4(float xv, int d[4]) {
  float c = fminf(fmaxf(xv, -7.999999f), 7.999999f);
  int m = (int)rintf(c * 268435456.0f);
#pragma unroll
  for (int t = 3; t >= 0; --t) {
    int dd = ((m + 128) & 255) - 128;
    d[t] = dd;
    m = (m - dd) >> 8;
  }
}

// async global->LDS, 16B per lane. LDS dest = wave-uniform base + lane*16.
__device__ __forceinline__ void gload16(const void* g, void* l) {
  __builtin_amdgcn_global_load_lds(
      (const __attribute__((address_space(1))) unsigned int*)(unsigned long long)g,
      (__attribute__((address_space(3))) unsigned int*)(unsigned long long)l,
      16, 0, 0);
}

// ===================== STORED-PLANE FAST PATH kernels =======================

// X [TB][C][N] f32 -> Xd4 [tb][n][4t][512c] i8 (transposed, MFMA-ready rows)
__global__ __launch_bounds__(256) void predig_x(
    const float* __restrict__ X, char* __restrict__ Xd4)
{
  const int cb = blockIdx.x * 64;
  const int nb = blockIdx.y * 64;
  const int tb = blockIdx.z;
  const int n  = threadIdx.x & 63;
  const int c0 = (threadIdx.x >> 6) * 16;
  int dg[16][4];
#pragma unroll
  for (int j = 0; j < 16; ++j) {
    float xv = X[((size_t)tb * C_ + cb + c0 + j) * N_ + nb + n];
    dig4(xv, dg[j]);
  }
#pragma unroll
  for (int t = 0; t < 4; ++t) {
    unsigned w[4];
#pragma unroll
    for (int q = 0; q < 4; ++q)
      w[q] = (unsigned)(dg[4*q+0][t] & 255)
           | ((unsigned)(dg[4*q+1][t] & 255) << 8)
           | ((unsigned)(dg[4*q+2][t] & 255) << 16)
           | ((unsigned)(dg[4*q+3][t] & 255) << 24);
    uint4 u; u.x = w[0]; u.y = w[1]; u.z = w[2]; u.w = w[3];
    *reinterpret_cast<uint4*>(
        &Xd4[(((size_t)tb * N_ + nb + n) * 4 + t) * C_ + cb + c0]) = u;
  }
}

// W [o][c] f32 -> Wsl [o][5s][512c] i8 interleaved, scale 2^39.
__global__ __launch_bounds__(128) void decomp_w5i(
    const float* __restrict__ W, char* __restrict__ Wsl)
{
  const int o = blockIdx.x;
  const int k4 = threadIdx.x * 4;
  float4 w4 = *reinterpret_cast<const float4*>(&W[(size_t)o * C_ + k4]);
  int d[4][5];
  digitize5(w4.x, 0x1p39, d[0]);
  digitize5(w4.y, 0x1p39, d[1]);
  digitize5(w4.z, 0x1p39, d[2]);
  digitize5(w4.w, 0x1p39, d[3]);
#pragma unroll
  for (int s = 0; s < 5; ++s) {
    unsigned u = (unsigned)(d[0][s] & 255) | ((unsigned)(d[1][s] & 255) << 8)
               | ((unsigned)(d[2][s] & 255) << 16) | ((unsigned)(d[3][s] & 255) << 24);
    *reinterpret_cast<unsigned*>(&Wsl[((size_t)o * 5 + s) * C_ + k4]) = u;
  }
}

// GEMM on pre-digitized planes — R15-proven staging (global_load_lds,
// source-side swizzle, linear LDS dest, 2-buffer + __syncthreads, grid
// (4,8,64) with the measured-perfect L2 locality). NEW wave tile:
// 16o x 64n per wave (4 waves cover 64o) -> A-loads per iter halve (10->5)
// while MFMA count/iter/wave stays 56 (XP=4). acc [u][nt] = 20 v4i (80
// regs, same bucket). Per-output accumulation chain (i asc, s-major pairs,
// same operands) identical to R10..R18 -> bit-identical Y.
// XP=4: B = Xd4 [tb][n][4][512], 14 pairs (s+t<=4), W0 = 2^-11
// XP=1: B = Sp8 [tb][n][512] binary, 5 pairs,        W0 = 2^-7
template<int XP>
__global__ __launch_bounds__(256) void gemm_s(
    const char* __restrict__ Bp, const char* __restrict__ Wsl,
    double* __restrict__ Y)
{
  __shared__ v4i Bls[2][XP][64][4];   // [buf][t][n][16B-slot]
  const int tb = blockIdx.z;
  const int ob = blockIdx.y * 64;
  const int nb = blockIdx.x * 64;
  const int tid = threadIdx.x;
  const int lane = tid & 63;
  const int wv = tid >> 6;          // 0..3
  const int wo = wv * 16;           // wave o-offset (16 rows)
  const int lr = lane & 15;
  const int lg = lane >> 4;

  v4i acc[5][4] = {};   // [u][nt] — 80 regs

  const char* a0 = Wsl + ((size_t)(ob + wo + lr) * 5) * C_ + lg * 16;

  // staging geometry: wave wv covers plane wv (XP=4) / row-group wv (XP=1).
  const int s_slot = lane & 3;
  const char* gsrc[(XP == 4) ? 4 : 1];
  if (XP == 4) {
#pragma unroll
    for (int r = 0; r < 4; ++r) {
      int sn = r * 16 + (lane >> 2);
      gsrc[r] = Bp + (((size_t)tb * N_ + nb + sn) * 4 + wv) * C_
              + ((s_slot ^ ((sn >> 1) & 3)) * 16);
    }
  } else {
    int sn = wv * 16 + (lane >> 2);
    gsrc[0] = Bp + ((size_t)tb * N_ + nb + sn) * C_
            + ((s_slot ^ ((sn >> 1) & 3)) * 16);
  }

#define STAGE_(buf, cb) do {                                              \
    if (XP == 4) {                                                        \
      _Pragma("unroll")                                                   \
      for (int r_ = 0; r_ < 4; ++r_)                                      \
        gload16(gsrc[r_] + (cb), &Bls[buf][wv][r_ * 16][0]);              \
    } else {                                                              \
      gload16(gsrc[0] + (cb), &Bls[buf][0][wv * 16][0]);                  \
    }                                                                     \
  } while (0)

  // prologue: stage chunk 0 into buf 0
  STAGE_(0, 0);
  __syncthreads();

#pragma unroll
  for (int i = 0; i < 8; ++i) {
    const int cur = i & 1;
    const int cb = i * 64;
    // A loads FIRST (older in vmcnt queue -> pre-MFMA wait leaves staging
    // in flight). Only 5 loads/iter now (16-row wave tile).
    v4i Af[5];
#pragma unroll
    for (int s = 0; s < 5; ++s)
      Af[s] = *reinterpret_cast<const v4i*>(a0 + (size_t)s * C_ + cb);
    __builtin_amdgcn_sched_barrier(0);
    if (i < 7) STAGE_(cur ^ 1, cb + 64);
    __builtin_amdgcn_sched_barrier(0);
    // B fragments from LDS: full 64-wide n (4 x 16-col groups)
    v4i Bf[XP][4];
#pragma unroll
    for (int t = 0; t < XP; ++t)
#pragma unroll
      for (int nt = 0; nt < 4; ++nt) {
        const int n = nt * 16 + lr;
        Bf[t][nt] = Bls[cur][t][n][lg ^ ((n >> 1) & 3)];
      }
    // MFMA cluster: 56 MFMA/wave/iter (XP=4), s-major pair order preserved
#pragma unroll
    for (int s = 0; s < 5; ++s)
#pragma unroll
      for (int t = 0; t < XP; ++t) {
        if (s + t <= 4) {
#pragma unroll
          for (int nt = 0; nt < 4; ++nt)
            acc[s + t][nt] = __builtin_amdgcn_mfma_i32_16x16x64_i8(
                Af[s], Bf[t][nt], acc[s + t][nt], 0, 0, 0);
        }
      }
    if (i < 7) __syncthreads();
  }
#undef STAGE_

  const double W0 = (XP == 4) ? 0x1p-11 : 0x1p-7;
#pragma unroll
  for (int nt = 0; nt < 4; ++nt)
#pragma unroll
    for (int r = 0; r < 4; ++r) {
      double y = 0.0;
      double wgt = W0;
#pragma unroll
      for (int u = 0; u < 5; ++u) {
        y = fma((double)acc[u][nt][r], wgt, y);
        wgt *= 0x1p-8;
      }
      int o = ob + wo + lg * 4 + r;
      int n = nb + nt * 16 + lr;
      Y[((size_t)tb * C_ + o) * N_ + n] = y;
    }
}

// BN stats partials: 4096 blocks (channel x 8 tb-groups). Deterministic.
__global__ __launch_bounds__(256) void bn_stats_part(
    const double* __restrict__ Y, double* __restrict__ part)
{
  const int ch = blockIdx.x >> 3;
  const int g  = blockIdx.x & 7;
  const int n = threadIdx.x;
  double s = 0.0, s2 = 0.0;
#pragma unroll
  for (int k = 0; k < 8; ++k) {
    int tb = g * 8 + k;
    double v = Y[((size_t)tb * C_ + ch) * N_ + n];
    s += v;
    s2 = fma(v, v, s2);
  }
  __shared__ double rs[256], rq[256];
  rs[n] = s; rq[n] = s2;
  __syncthreads();
  for (int off = 128; off > 0; off >>= 1) {
    if (n < off) { rs[n] += rs[n + off]; rq[n] += rq[n + off]; }
    __syncthreads();
  }
  if (n == 0) {
    part[(size_t)(ch * 8 + g) * 2]     = rs[0];
    part[(size_t)(ch * 8 + g) * 2 + 1] = rq[0];
  }
}

// finalize stats inline (identical fixed g-order to the old bn_stats_fin)
__device__ __forceinline__ void stats_from_part(
    const double* __restrict__ part, int ch, double& mu, double& rsig)
{
  double s = 0.0, s2 = 0.0;
#pragma unroll
  for (int g = 0; g < 8; ++g) {
    s  += part[(size_t)(ch * 8 + g) * 2];
    s2 += part[(size_t)(ch * 8 + g) * 2 + 1];
  }
  mu = s * (1.0 / 16384.0);
  double var = s2 * (1.0 / 16384.0) - mu * mu;
  rsig = 1.0 / sqrt(var + 1e-5);
}

// Attention producing i16 counts (a = 0.125 * count applied later).
__global__ __launch_bounds__(256) void attn16(
    const u64* __restrict__ qb, const u64* __restrict__ kb,
    const u64* __restrict__ vb, short* __restrict__ A16)
{
  __shared__ u64 kw[64][4], vw[64][4], qw[64][4];
  __shared__ int kvs[64][64];
  const int h  = blockIdx.x & 7;
  const int tb = blockIdx.x >> 3;
  const int tid = threadIdx.x;
  {
    int dd = tid >> 2, w = tid & 3;
    size_t base = ((size_t)tb * C_ + h * 64 + dd) * 4 + w;
    kw[dd][w] = kb[base];
    vw[dd][w] = vb[base];
    qw[dd][w] = qb[base];
  }
  __syncthreads();
  {
    int dd = tid >> 2;
    int e0 = (tid & 3) << 4;
    u64 k0 = kw[dd][0], k1 = kw[dd][1], k2 = kw[dd][2], k3 = kw[dd][3];
    for (int e = e0; e < e0 + 16; ++e) {
      int c = __popcll(k0 & vw[e][0]) + __popcll(k1 & vw[e][1])
            + __popcll(k2 & vw[e][2]) + __popcll(k3 & vw[e][3]);
      kvs[dd][e] = c;
    }
  }
  __syncthreads();
  const int n = tid;
  u64 qmask = 0;
  {
    int wsel = n >> 6, sh = n & 63;
#pragma unroll
    for (int dd = 0; dd < 64; ++dd)
      qmask |= ((qw[dd][wsel] >> sh) & 1ull) << dd;
  }
  short* Ap = A16 + ((size_t)tb * C_ + h * 64) * N_ + n;
  for (int e = 0; e < 64; ++e) {
    int s = 0;
#pragma unroll
    for (int dd = 0; dd < 64; ++dd) {
      int m = -(int)((qmask >> dd) & 1ull);
      s += kvs[dd][e] & m;
    }
    Ap[(size_t)e * N_] = (short)s;
  }
}

// attn LIF (vth=0.5, exact fp32 on dyadics) -> binary i8 spikes transposed
// Sp8 [tb][n][512c].
__global__ __launch_bounds__(256) void attn_lif_sp(
    const short* __restrict__ A16, char* __restrict__ Sp8)
{
  const int nb = blockIdx.x * 64;
  const int cb = blockIdx.y * 64;
  const int b  = blockIdx.z;
  const int n  = threadIdx.x & 63;
  const int c0 = (threadIdx.x >> 6) * 16;
  unsigned char sp[4][16];
#pragma unroll
  for (int j = 0; j < 16; ++j) {
    int c = cb + c0 + j;
    float v = 0.f;
#pragma unroll
    for (int t = 0; t < T_; ++t) {
      float a = 0.125f * (float)A16[((size_t)(t * B_ + b) * C_ + c) * N_ + nb + n];
      v = (v + a) * 0.5f;
      bool s = (v >= 0.5f);
      sp[t][j] = s ? 1 : 0;
      if (s) v = 0.f;
    }
  }
#pragma unroll
  for (int t = 0; t < T_; ++t) {
    unsigned w[4];
#pragma unroll
    for (int q = 0; q < 4; ++q)
      w[q] = (unsigned)sp[t][4*q+0] | ((unsigned)sp[t][4*q+1] << 8)
           | ((unsigned)sp[t][4*q+2] << 16) | ((unsigned)sp[t][4*q+3] << 24);
    uint4 u; u.x = w[0]; u.y = w[1]; u.z = w[2]; u.w = w[3];
    *reinterpret_cast<uint4*>(
        &Sp8[((size_t)(t * B_ + b) * N_ + nb + n) * C_ + cb + c0]) = u;
  }
}

// BN-normalize + 4-step LIF (stats finalized inline from partials).
__global__ __launch_bounds__(256) void bn_lif_bits(
    const double* __restrict__ Y, const double* __restrict__ part,
    const float* __restrict__ gamma, const float* __restrict__ beta,
    double vth, u64* __restrict__ bits)
{
  const int o = blockIdx.x & (C_ - 1);
  const int b = blockIdx.x >> 9;
  const int n = threadIdx.x;
  double mu, rsig;
  stats_from_part(part, o, mu, rsig);
  const double g = (double)gamma[o], be = (double)beta[o];
  double v = 0.0;
#pragma unroll
  for (int t = 0; t < T_; ++t) {
    double y  = Y[((size_t)(t * B_ + b) * C_ + o) * N_ + n];
    double yn = (y - mu) * rsig * g + be;
    v = v + (yn - v) * 0.5;
    bool sp = (v >= vth);
    u64 m = __ballot(sp);
    if ((n & 63) == 0)
      bits[((size_t)(t * B_ + b) * C_ + o) * (N_ / 64) + (n >> 6)] = m;
    if (sp) v = 0.0;
  }
}

__global__ __launch_bounds__(256) void bn_lif_out(
    const double* __restrict__ Y, const double* __restrict__ part,
    const float* __restrict__ gamma, const float* __restrict__ beta,
    float* __restrict__ out)
{
  const int o = blockIdx.x & (C_ - 1);
  const int b = blockIdx.x >> 9;
  const int n = threadIdx.x;
  double mu, rsig;
  stats_from_part(part, o, mu, rsig);
  const double g = (double)gamma[o], be = (double)beta[o];
  double v = 0.0;
#pragma unroll
  for (int t = 0; t < T_; ++t) {
    double y  = Y[((size_t)(t * B_ + b) * C_ + o) * N_ + n];
    double yn = (y - mu) * rsig * g + be;
    v = v + (yn - v) * 0.5;
    bool sp = (v >= 1.0);
    out[((size_t)(t * B_ + b) * C_ + o) * N_ + n] = sp ? 1.0f : 0.0f;
    if (sp) v = 0.0;
  }
}

// ===================== FALLBACK (R4, proven) kernels ========================

__global__ __launch_bounds__(128) void decomp_w(
    const float* __restrict__ W, char* __restrict__ Wsl)
{
  const int o = blockIdx.x;
  const int k4 = threadIdx.x * 4;
  float4 w4 = *reinterpret_cast<const float4*>(&W[(size_t)o * C_ + k4]);
  int d[4][6];
  digitize6(w4.x, 0x1p47, d[0]);
  digitize6(w4.y, 0x1p47, d[1]);
  digitize6(w4.z, 0x1p47, d[2]);
  digitize6(w4.w, 0x1p47, d[3]);
#pragma unroll
  for (int s = 0; s < 6; ++s) {
    unsigned u = (unsigned)(d[0][s] & 255) | ((unsigned)(d[1][s] & 255) << 8)
               | ((unsigned)(d[2][s] & 255) << 16) | ((unsigned)(d[3][s] & 255) << 24);
    *reinterpret_cast<unsigned*>(&Wsl[(size_t)s * C_ * C_ + (size_t)o * C_ + k4]) = u;
  }
}

template<int XS>
__global__ __launch_bounds__(256) void gemm_i8(
    const float* __restrict__ X, const char* __restrict__ Wsl,
    double* __restrict__ Y)
{
  __shared__ char Xs[XS][64][72];
  const int tb = blockIdx.z;
  const int ob = blockIdx.y * 64;
  const int nb = blockIdx.x * 64;
  const int tid = threadIdx.x;
  const int lane = tid & 63;
  const int wv = tid >> 6;
  const int wo = (wv & 1) * 32;
  const int wn = (wv >> 1) * 32;
  const int lr = lane & 15;
  const int lg = lane >> 4;

  constexpr int NU = (XS == 6) ? 7 : 6;
  v4i acc[NU][2][2] = {};

  const int sn = tid & 63;
  const int kq = (tid >> 6) * 4;

  for (int cb = 0; cb < C_; cb += 64) {
    __syncthreads();
#pragma unroll
    for (int st = 0; st < 4; ++st) {
      int k0 = kq + 16 * st;
      int dg[4][6];
#pragma unroll
      for (int j = 0; j < 4; ++j) {
        float xv = X[((size_t)tb * C_ + cb + k0 + j) * N_ + nb + sn];
        digitize6(xv, 0x1p43, dg[j]);
      }
#pragma unroll
      for (int t = 0; t < XS; ++t) {
        unsigned u = (unsigned)(dg[0][t] & 255) | ((unsigned)(dg[1][t] & 255) << 8)
                   | ((unsigned)(dg[2][t] & 255) << 16) | ((unsigned)(dg[3][t] & 255) << 24);
        *reinterpret_cast<unsigned*>(&Xs[t][sn][k0]) = u;
      }
    }
    __syncthreads();

    v4i Bf[XS][2];
#pragma unroll
    for (int t = 0; t < XS; ++t)
#pragma unroll
      for (int nt = 0; nt < 2; ++nt) {
        const char* p = &Xs[t][wn + nt * 16 + lr][lg * 16];
        int2 lo = *reinterpret_cast<const int2*>(p);
        int2 hi = *reinterpret_cast<const int2*>(p + 8);
        v4i b; b[0] = lo.x; b[1] = lo.y; b[2] = hi.x; b[3] = hi.y;
        Bf[t][nt] = b;
      }

#pragma unroll
    for (int s = 0; s < 6; ++s) {
      v4i Af[2];
#pragma unroll
      for (int ot = 0; ot < 2; ++ot) {
        const char* ap = Wsl + (size_t)s * C_ * C_
                       + (size_t)(ob + wo + ot * 16 + lr) * C_ + cb + lg * 16;
        Af[ot] = *reinterpret_cast<const v4i*>(ap);
      }
#pragma unroll
      for (int t = 0; t < XS; ++t) {
        if (s + t <= 6) {
#pragma unroll
          for (int ot = 0; ot < 2; ++ot)
#pragma unroll
            for (int nt = 0; nt < 2; ++nt)
              acc[s + t][ot][nt] = __builtin_amdgcn_mfma_i32_16x16x64_i8(
                  Af[ot], Bf[t][nt], acc[s + t][ot][nt], 0, 0, 0);
        }
      }
    }
  }

  const double WGT[7] = {0x1p-10, 0x1p-18, 0x1p-26, 0x1p-34,
                         0x1p-42, 0x1p-50, 0x1p-58};
#pragma unroll
  for (int ot = 0; ot < 2; ++ot)
#pragma unroll
    for (int nt = 0; nt < 2; ++nt)
#pragma unroll
      for (int r = 0; r < 4; ++r) {
        double y = 0.0;
#pragma unroll
        for (int u = 0; u < NU; ++u)
          y = fma((double)acc[u][ot][nt][r], WGT[u], y);
        int o = ob + wo + ot * 16 + lg * 4 + r;
        int n = nb + wn + nt * 16 + lr;
        Y[((size_t)tb * C_ + o) * N_ + n] = y;
      }
}

__global__ __launch_bounds__(256) void attn_kernel(
    const u64* __restrict__ qb, const u64* __restrict__ kb,
    const u64* __restrict__ vb, float* __restrict__ A)
{
  __shared__ u64 kw[64][4], vw[64][4], qw[64][4];
  __shared__ int kvs[64][64];
  const int h  = blockIdx.x & 7;
  const int tb = blockIdx.x >> 3;
  const int tid = threadIdx.x;
  {
    int dd = tid >> 2, w = tid & 3;
    size_t base = ((size_t)tb * C_ + h * 64 + dd) * 4 + w;
    kw[dd][w] = kb[base];
    vw[dd][w] = vb[base];
    qw[dd][w] = qb[base];
  }
  __syncthreads();
  {
    int dd = tid >> 2;
    int e0 = (tid & 3) << 4;
    u64 k0 = kw[dd][0], k1 = kw[dd][1], k2 = kw[dd][2], k3 = kw[dd][3];
    for (int e = e0; e < e0 + 16; ++e) {
      int c = __popcll(k0 & vw[e][0]) + __popcll(k1 & vw[e][1])
            + __popcll(k2 & vw[e][2]) + __popcll(k3 & vw[e][3]);
      kvs[dd][e] = c;
    }
  }
  __syncthreads();
  const int n = tid;
  u64 qmask = 0;
  {
    int wsel = n >> 6, sh = n & 63;
#pragma unroll
    for (int dd = 0; dd < 64; ++dd)
      qmask |= ((qw[dd][wsel] >> sh) & 1ull) << dd;
  }
  float* Ap = A + ((size_t)tb * C_ + h * 64) * N_ + n;
  for (int e = 0; e < 64; ++e) {
    int s = 0;
#pragma unroll
    for (int dd = 0; dd < 64; ++dd) {
      int m = -(int)((qmask >> dd) & 1ull);
      s += kvs[dd][e] & m;
    }
    Ap[(size_t)e * N_] = (float)s * 0.125f;
  }
}

__global__ __launch_bounds__(256) void attn_lif(float* __restrict__ A)
{
  const size_t i = (size_t)blockIdx.x * 256 + threadIdx.x;
  const size_t stride = (size_t)B_ * C_ * N_;
  float v = 0.f;
#pragma unroll
  for (int t = 0; t < T_; ++t) {
    float a = A[t * stride + i];
    v = v + (a - v) * 0.5f;
    bool sp = (v >= 0.5f);
    A[t * stride + i] = sp ? 1.0f : 0.0f;
    if (sp) v = 0.f;
  }
}

__global__ __launch_bounds__(256) void bn_stats(
    const double* __restrict__ Y, double* __restrict__ stats)
{
  const int o = blockIdx.x;
  const int n = threadIdx.x;
  double s = 0.0, s2 = 0.0;
  for (int tb = 0; tb < TB_; ++tb) {
    double v = Y[((size_t)tb * C_ + o) * N_ + n];
    s += v;
    s2 = fma(v, v, s2);
  }
  __shared__ double rs[256], rq[256];
  rs[n] = s; rq[n] = s2;
  __syncthreads();
  for (int off = 128; off > 0; off >>= 1) {
    if (n < off) { rs[n] += rs[n + off]; rq[n] += rq[n + off]; }
    __syncthreads();
  }
  if (n == 0) {
    double mu  = rs[0] * (1.0 / 16384.0);
    double var = rq[0] * (1.0 / 16384.0) - mu * mu;
    stats[o]      = mu;
    stats[C_ + o] = 1.0 / sqrt(var + 1e-5);
  }
}

__global__ __launch_bounds__(256) void bn_lif_bits_fb(
    const double* __restrict__ Y, const double* __restrict__ stats,
    const float* __restrict__ gamma, const float* __restrict__ beta,
    double vth, u64* __restrict__ bits)
{
  const int o = blockIdx.x & (C_ - 1);
  const int b = blockIdx.x >> 9;
  const int n = threadIdx.x;
  const double mu = stats[o], rsig = stats[C_ + o];
  const double g = (double)gamma[o], be = (double)beta[o];
  double v = 0.0;
#pragma unroll
  for (int t = 0; t < T_; ++t) {
    double y  = Y[((size_t)(t * B_ + b) * C_ + o) * N_ + n];
    double yn = (y - mu) * rsig * g + be;
    v = v + (yn - v) * 0.5;
    bool sp = (v >= vth);
    u64 m = __ballot(sp);
    if ((n & 63) == 0)
      bits[((size_t)(t * B_ + b) * C_ + o) * (N_ / 64) + (n >> 6)] = m;
    if (sp) v = 0.0;
  }
}

__global__ __launch_bounds__(256) void bn_lif_out_fb(
    const double* __restrict__ Y, const double* __restrict__ stats,
    const float* __restrict__ gamma, const float* __restrict__ beta,
    float* __restrict__ out)
{
  const int o = blockIdx.x & (C_ - 1);
  const int b = blockIdx.x >> 9;
  const int n = threadIdx.x;
  const double mu = stats[o], rsig = stats[C_ + o];
  const double g = (double)gamma[o], be = (double)beta[o];
  double v = 0.0;
#pragma unroll
  for (int t = 0; t < T_; ++t) {
    double y  = Y[((size_t)(t * B_ + b) * C_ + o) * N_ + n];
    double yn = (y - mu) * rsig * g + be;
    v = v + (yn - v) * 0.5;
    bool sp = (v >= 1.0);
    out[((size_t)(t * B_ + b) * C_ + o) * N_ + n] = sp ? 1.0f : 0.0f;
    if (sp) v = 0.0;
  }
}

// ---------------------------------------------------------------------------
extern "C" void kernel_launch(void* const* d_in, const int* in_sizes, int n_in,
                              void* d_out, int out_size, void* d_ws, size_t ws_size,
                              hipStream_t stream)
{
  const float* x    = (const float*)d_in[0];
  const float* qW   = (const float*)d_in[1];
  const float* qg   = (const float*)d_in[2];
  const float* qbt  = (const float*)d_in[3];
  const float* kW   = (const float*)d_in[4];
  const float* kg   = (const float*)d_in[5];
  const float* kbt  = (const float*)d_in[6];
  const float* vW   = (const float*)d_in[7];
  const float* vg   = (const float*)d_in[8];
  const float* vbt  = (const float*)d_in[9];
  const float* pW   = (const float*)d_in[10];
  // d_in[11] proj_b cancels exactly under BN mean subtraction -> unused
  const float* pg   = (const float*)d_in[12];
  const float* pbt  = (const float*)d_in[13];

  char* ws = (char*)d_ws;
  double* yD    = (double*)ws;                    // 67,108,864 B
  u64*    bitsQ = (u64*)(ws + 100663296);         //  1,048,576 B
  u64*    bitsK = (u64*)(ws + 101711872);         //  1,048,576 B
  u64*    bitsV = (u64*)(ws + 102760448);         //  1,048,576 B
  double* stats = (double*)(ws + 103809024);      //      8,192 B

  if (ws_size >= 105390080ull) {
    // ---------------- fast path: pre-digitized operand planes ----------------
    char*   Xd4  = ws + 67108864;                 // 33,554,432 B (dead after V)
    short*  A16  = (short*)(ws + 67108864);       // 16,777,216 B (after V gemm)
    char*   Sp8  = ws + 67108864 + 16777216;      //  8,388,608 B
    char*   Wsl5 = ws + 103817216;                //  1,310,720 B
    double* part = (double*)(ws + 105127936);     //     65,536 B

    dim3 ggrid(4, 8, 64);

    predig_x<<<dim3(8, 4, 64), 256, 0, stream>>>(x, Xd4);
    // Q
    decomp_w5i<<<512, 128, 0, stream>>>(qW, Wsl5);
    gemm_s<4><<<ggrid, 256, 0, stream>>>(Xd4, Wsl5, yD);
    bn_stats_part<<<4096, 256, 0, stream>>>(yD, part);
    bn_lif_bits<<<8192, 256, 0, stream>>>(yD, part, qg, qbt, 1.0, bitsQ);
    // K
    decomp_w5i<<<512, 128, 0, stream>>>(kW, Wsl5);
    gemm_s<4><<<ggrid, 256, 0, stream>>>(Xd4, Wsl5, yD);
    bn_stats_part<<<4096, 256, 0, stream>>>(yD, part);
    bn_lif_bits<<<8192, 256, 0, stream>>>(yD, part, kg, kbt, 1.0, bitsK);
    // V
    decomp_w5i<<<512, 128, 0, stream>>>(vW, Wsl5);
    gemm_s<4><<<ggrid, 256, 0, stream>>>(Xd4, Wsl5, yD);
    bn_stats_part<<<4096, 256, 0, stream>>>(yD, part);
    bn_lif_bits<<<8192, 256, 0, stream>>>(yD, part, vg, vbt, 1.0, bitsV);
    // attention (exact int) + LIF -> transposed binary i8 (overwrites Xd4)
    attn16<<<512, 256, 0, stream>>>(bitsQ, bitsK, bitsV, A16);
    attn_lif_sp<<<dim3(4, 8, 16), 256, 0, stream>>>(A16, Sp8);
    // projection (binary B, 5 w-digits)
    decomp_w5i<<<512, 128, 0, stream>>>(pW, Wsl5);
    gemm_s<1><<<ggrid, 256, 0, stream>>>(Sp8, Wsl5, yD);
    bn_stats_part<<<4096, 256, 0, stream>>>(yD, part);
    bn_lif_out<<<8192, 256, 0, stream>>>(yD, part, pg, pbt, (float*)d_out);
  } else {
    // ---------------- fallback: proven R4 pipeline ----------------
    float* A    = (float*)(ws + 67108864);
    char*  WslA = ws + 67108864;
    char*  WslB = ws + 100663296;

    dim3 ggrid(4, 8, 64);

    decomp_w<<<512, 128, 0, stream>>>(qW, WslA);
    gemm_i8<6><<<ggrid, 256, 0, stream>>>(x, WslA, yD);
    bn_stats<<<512, 256, 0, stream>>>(yD, stats);
    bn_lif_bits_fb<<<8192, 256, 0, stream>>>(yD, stats, qg, qbt, 1.0, bitsQ);
    decomp_w<<<512, 128, 0, stream>>>(kW, WslA);
    gemm_i8<6><<<ggrid, 256, 0, stream>>>(x, WslA, yD);
    bn_stats<<<512, 256, 0, stream>>>(yD, stats);
    bn_lif_bits_fb<<<8192, 256, 0, stream>>>(yD, stats, kg, kbt, 1.0, bitsK);
    decomp_w<<<512, 128, 0, stream>>>(vW, WslA);
    gemm_i8<6><<<ggrid, 256, 0, stream>>>(x, WslA, yD);
    bn_stats<<<512, 256, 0, stream>>>(yD, stats);
    bn_lif_bits_fb<<<8192, 256, 0, stream>>>(yD, stats, vg, vbt, 1.0, bitsV);
    attn_kernel<<<512, 256, 0, stream>>>(bitsQ, bitsK, bitsV, A);
    attn_lif<<<8192, 256, 0, stream>>>(A);
    decomp_w<<<512, 128, 0, stream>>>(pW, WslB);
    gemm_i8<1><<<ggrid, 256, 0, stream>>>(A, WslB, yD);
    bn_stats<<<512, 256, 0, stream>>>(yD, stats);
    bn_lif_out_fb<<<8192, 256, 0, stream>>>(yD, stats, pg, pbt, (float*)d_out);
  }
}

// Round 20
// 408.056 us; speedup vs baseline: 2.0084x; 1.0590x over previous
//
#include <hip/hip_runtime.h>

#define T_ 4
#define B_ 16
#define C_ 512
#define N_ 256
#define TB_ 64

using u64 = unsigned long long;
typedef int v4i __attribute__((ext_vector_type(4)));

// ============================ shared helpers ================================

__device__ __forceinline__ void digitize6(float xf, double scale, int d[6]) {
  double m = (double)xf * scale;
  long long t = (long long)rint(m);
#pragma unroll
  for (int s = 5; s >= 0; --s) {
    int dig = (int)((t + 128) & 255) - 128;
    d[s] = dig;
    t = (t - dig) >> 8;
  }
}

__device__ __forceinline__ void digitize5(float xf, double scale, int d[5]) {
  double m = (double)xf * scale;
  long long t = (long long)rint(m);
#pragma unroll
  for (int s = 4; s >= 0; --s) {
    int dig = (int)((t + 128) & 255) - 128;
    d[s] = dig;
    t = (t - dig) >> 8;
  }
}

// 4-digit balanced base-256, S=2^28 (span +-8; exact for |x|>=2^-5 fp32).
__device__ __forceinline__ void dig4(float xv, int d[4]) {
  float c = fminf(fmaxf(xv, -7.999999f), 7.999999f);
  int m = (int)rintf(c * 268435456.0f);
#pragma unroll
  for (int t = 3; t >= 0; --t) {
    int dd = ((m + 128) & 255) - 128;
    d[t] = dd;
    m = (m - dd) >> 8;
  }
}

// async global->LDS, 16B per lane. LDS dest = wave-uniform base + lane*16.
__device__ __forceinline__ void gload16(const void* g, void* l) {
  __builtin_amdgcn_global_load_lds(
      (const __attribute__((address_space(1))) unsigned int*)(unsigned long long)g,
      (__attribute__((address_space(3))) unsigned int*)(unsigned long long)l,
      16, 0, 0);
}

// ===================== STORED-PLANE FAST PATH kernels =======================

// X [TB][C][N] f32 -> Xd4 [tb][n][4t][512c] i8 (transposed, MFMA-ready rows)
__global__ __launch_bounds__(256) void predig_x(
    const float* __restrict__ X, char* __restrict__ Xd4)
{
  const int cb = blockIdx.x * 64;
  const int nb = blockIdx.y * 64;
  const int tb = blockIdx.z;
  const int n  = threadIdx.x & 63;
  const int c0 = (threadIdx.x >> 6) * 16;
  int dg[16][4];
#pragma unroll
  for (int j = 0; j < 16; ++j) {
    float xv = X[((size_t)tb * C_ + cb + c0 + j) * N_ + nb + n];
    dig4(xv, dg[j]);
  }
#pragma unroll
  for (int t = 0; t < 4; ++t) {
    unsigned w[4];
#pragma unroll
    for (int q = 0; q < 4; ++q)
      w[q] = (unsigned)(dg[4*q+0][t] & 255)
           | ((unsigned)(dg[4*q+1][t] & 255) << 8)
           | ((unsigned)(dg[4*q+2][t] & 255) << 16)
           | ((unsigned)(dg[4*q+3][t] & 255) << 24);
    uint4 u; u.x = w[0]; u.y = w[1]; u.z = w[2]; u.w = w[3];
    *reinterpret_cast<uint4*>(
        &Xd4[(((size_t)tb * N_ + nb + n) * 4 + t) * C_ + cb + c0]) = u;
  }
}

// W [o][c] f32 -> Wsl [o][5s][512c] i8 interleaved, scale 2^39.
__global__ __launch_bounds__(128) void decomp_w5i(
    const float* __restrict__ W, char* __restrict__ Wsl)
{
  const int o = blockIdx.x;
  const int k4 = threadIdx.x * 4;
  float4 w4 = *reinterpret_cast<const float4*>(&W[(size_t)o * C_ + k4]);
  int d[4][5];
  digitize5(w4.x, 0x1p39, d[0]);
  digitize5(w4.y, 0x1p39, d[1]);
  digitize5(w4.z, 0x1p39, d[2]);
  digitize5(w4.w, 0x1p39, d[3]);
#pragma unroll
  for (int s = 0; s < 5; ++s) {
    unsigned u = (unsigned)(d[0][s] & 255) | ((unsigned)(d[1][s] & 255) << 8)
               | ((unsigned)(d[2][s] & 255) << 16) | ((unsigned)(d[3][s] & 255) << 24);
    *reinterpret_cast<unsigned*>(&Wsl[((size_t)o * 5 + s) * C_ + k4]) = u;
  }
}

// GEMM on pre-digitized planes — BOTH operands staged via global_load_lds
// (full async pipeline: zero vmcnt waits in the compute chain; ds_read +
// MFMA only). A-tile 20KB/chunk in LDS, XOR-swizzled identically to B
// (source pre-swizzle + swizzled read = identity -> each lane reads the
// SAME bytes as R19 -> bit-identical Y). Wave tile 16o x 64n (R19-proven),
// 2-buffer + __syncthreads (drain lands >=1 full iter after stage issue).
// XP=4: B = Xd4 [tb][n][4][512], 14 pairs (s+t<=4), W0 = 2^-11
// XP=1: B = Sp8 [tb][n][512] binary, 5 pairs,        W0 = 2^-7
template<int XP>
__global__ __launch_bounds__(256) void gemm_s(
    const char* __restrict__ Bp, const char* __restrict__ Wsl,
    double* __restrict__ Y)
{
  __shared__ v4i Als[2][5][64][4];    // [buf][s][o][slot] 40KB
  __shared__ v4i Bls[2][XP][64][4];   // [buf][t][n][slot] 32KB/8KB
  const int tb = blockIdx.z;
  const int ob = blockIdx.y * 64;
  const int nb = blockIdx.x * 64;
  const int tid = threadIdx.x;
  const int lane = tid & 63;
  const int wv = tid >> 6;          // 0..3
  const int wo = wv * 16;           // wave o-offset
  const int lr = lane & 15;
  const int lg = lane >> 4;

  v4i acc[5][4] = {};   // [u][nt] — 80 regs

  // ---- A staging geometry: wave wv covers o-quarter [wv*16, wv*16+16),
  // one gload16 per s (lane l -> o = wv*16 + (l>>2), slot = l&3; global
  // source cgroup = slot ^ ((o>>1)&3), so swizzled-read returns cgroup lg).
  const int sow = wv * 16 + (lane >> 2);
  const int acs = (lane & 3) ^ ((sow >> 1) & 3);
  const char* asrc[5];
#pragma unroll
  for (int s = 0; s < 5; ++s)
    asrc[s] = Wsl + ((size_t)(ob + sow) * 5 + s) * C_ + acs * 16;

  // ---- B staging geometry (R15/R19-proven): wave wv covers plane wv
  // (XP=4, 4 gloads) / row-group wv (XP=1, 1 gload).
  const int s_slot = lane & 3;
  const char* bsrc[(XP == 4) ? 4 : 1];
  if (XP == 4) {
#pragma unroll
    for (int r = 0; r < 4; ++r) {
      int sn = r * 16 + (lane >> 2);
      bsrc[r] = Bp + (((size_t)tb * N_ + nb + sn) * 4 + wv) * C_
              + ((s_slot ^ ((sn >> 1) & 3)) * 16);
    }
  } else {
    int sn = wv * 16 + (lane >> 2);
    bsrc[0] = Bp + ((size_t)tb * N_ + nb + sn) * C_
            + ((s_slot ^ ((sn >> 1) & 3)) * 16);
  }

#define STAGE_(buf, cb) do {                                              \
    _Pragma("unroll")                                                     \
    for (int s_ = 0; s_ < 5; ++s_)                                        \
      gload16(asrc[s_] + (cb), &Als[buf][s_][wv * 16][0]);                \
    if (XP == 4) {                                                        \
      _Pragma("unroll")                                                   \
      for (int r_ = 0; r_ < 4; ++r_)                                      \
        gload16(bsrc[r_] + (cb), &Bls[buf][wv][r_ * 16][0]);              \
    } else {                                                              \
      gload16(bsrc[0] + (cb), &Bls[buf][0][wv * 16][0]);                  \
    }                                                                     \
  } while (0)

  // prologue: stage chunk 0 into buf 0 (syncthreads drains vmcnt)
  STAGE_(0, 0);
  __syncthreads();

#pragma unroll
  for (int i = 0; i < 8; ++i) {
    const int cur = i & 1;
    const int cb = i * 64;
    // issue next-chunk stage FIRST (async; drained by end-of-iter barrier,
    // a full MFMA cluster later). No vmcnt wait in this iter's chain.
    if (i < 7) STAGE_(cur ^ 1, cb + 64);
    __builtin_amdgcn_sched_barrier(0);
    // A fragments from LDS (swizzled read = source pre-swizzle inverse)
    v4i Af[5];
#pragma unroll
    for (int s = 0; s < 5; ++s) {
      const int o = wo + lr;
      Af[s] = Als[cur][s][o][lg ^ ((o >> 1) & 3)];
    }
    // B fragments from LDS
    v4i Bf[XP][4];
#pragma unroll
    for (int t = 0; t < XP; ++t)
#pragma unroll
      for (int nt = 0; nt < 4; ++nt) {
        const int n = nt * 16 + lr;
        Bf[t][nt] = Bls[cur][t][n][lg ^ ((n >> 1) & 3)];
      }
    // MFMA cluster: 56/wave/iter (XP=4), s-major pair order preserved
#pragma unroll
    for (int s = 0; s < 5; ++s)
#pragma unroll
      for (int t = 0; t < XP; ++t) {
        if (s + t <= 4) {
#pragma unroll
          for (int nt = 0; nt < 4; ++nt)
            acc[s + t][nt] = __builtin_amdgcn_mfma_i32_16x16x64_i8(
                Af[s], Bf[t][nt], acc[s + t][nt], 0, 0, 0);
        }
      }
    if (i < 7) __syncthreads();
  }
#undef STAGE_

  const double W0 = (XP == 4) ? 0x1p-11 : 0x1p-7;
#pragma unroll
  for (int nt = 0; nt < 4; ++nt)
#pragma unroll
    for (int r = 0; r < 4; ++r) {
      double y = 0.0;
      double wgt = W0;
#pragma unroll
      for (int u = 0; u < 5; ++u) {
        y = fma((double)acc[u][nt][r], wgt, y);
        wgt *= 0x1p-8;
      }
      int o = ob + wo + lg * 4 + r;
      int n = nb + nt * 16 + lr;
      Y[((size_t)tb * C_ + o) * N_ + n] = y;
    }
}

// BN stats partials: 4096 blocks (channel x 8 tb-groups). Deterministic.
__global__ __launch_bounds__(256) void bn_stats_part(
    const double* __restrict__ Y, double* __restrict__ part)
{
  const int ch = blockIdx.x >> 3;
  const int g  = blockIdx.x & 7;
  const int n = threadIdx.x;
  double s = 0.0, s2 = 0.0;
#pragma unroll
  for (int k = 0; k < 8; ++k) {
    int tb = g * 8 + k;
    double v = Y[((size_t)tb * C_ + ch) * N_ + n];
    s += v;
    s2 = fma(v, v, s2);
  }
  __shared__ double rs[256], rq[256];
  rs[n] = s; rq[n] = s2;
  __syncthreads();
  for (int off = 128; off > 0; off >>= 1) {
    if (n < off) { rs[n] += rs[n + off]; rq[n] += rq[n + off]; }
    __syncthreads();
  }
  if (n == 0) {
    part[(size_t)(ch * 8 + g) * 2]     = rs[0];
    part[(size_t)(ch * 8 + g) * 2 + 1] = rq[0];
  }
}

// finalize stats inline (identical fixed g-order)
__device__ __forceinline__ void stats_from_part(
    const double* __restrict__ part, int ch, double& mu, double& rsig)
{
  double s = 0.0, s2 = 0.0;
#pragma unroll
  for (int g = 0; g < 8; ++g) {
    s  += part[(size_t)(ch * 8 + g) * 2];
    s2 += part[(size_t)(ch * 8 + g) * 2 + 1];
  }
  mu = s * (1.0 / 16384.0);
  double var = s2 * (1.0 / 16384.0) - mu * mu;
  rsig = 1.0 / sqrt(var + 1e-5);
}

// Attention producing i16 counts (a = 0.125 * count applied later).
__global__ __launch_bounds__(256) void attn16(
    const u64* __restrict__ qb, const u64* __restrict__ kb,
    const u64* __restrict__ vb, short* __restrict__ A16)
{
  __shared__ u64 kw[64][4], vw[64][4], qw[64][4];
  __shared__ int kvs[64][64];
  const int h  = blockIdx.x & 7;
  const int tb = blockIdx.x >> 3;
  const int tid = threadIdx.x;
  {
    int dd = tid >> 2, w = tid & 3;
    size_t base = ((size_t)tb * C_ + h * 64 + dd) * 4 + w;
    kw[dd][w] = kb[base];
    vw[dd][w] = vb[base];
    qw[dd][w] = qb[base];
  }
  __syncthreads();
  {
    int dd = tid >> 2;
    int e0 = (tid & 3) << 4;
    u64 k0 = kw[dd][0], k1 = kw[dd][1], k2 = kw[dd][2], k3 = kw[dd][3];
    for (int e = e0; e < e0 + 16; ++e) {
      int c = __popcll(k0 & vw[e][0]) + __popcll(k1 & vw[e][1])
            + __popcll(k2 & vw[e][2]) + __popcll(k3 & vw[e][3]);
      kvs[dd][e] = c;
    }
  }
  __syncthreads();
  const int n = tid;
  u64 qmask = 0;
  {
    int wsel = n >> 6, sh = n & 63;
#pragma unroll
    for (int dd = 0; dd < 64; ++dd)
      qmask |= ((qw[dd][wsel] >> sh) & 1ull) << dd;
  }
  short* Ap = A16 + ((size_t)tb * C_ + h * 64) * N_ + n;
  for (int e = 0; e < 64; ++e) {
    int s = 0;
#pragma unroll
    for (int dd = 0; dd < 64; ++dd) {
      int m = -(int)((qmask >> dd) & 1ull);
      s += kvs[dd][e] & m;
    }
    Ap[(size_t)e * N_] = (short)s;
  }
}

// attn LIF (vth=0.5, exact fp32 on dyadics) -> binary i8 spikes transposed
// Sp8 [tb][n][512c].
__global__ __launch_bounds__(256) void attn_lif_sp(
    const short* __restrict__ A16, char* __restrict__ Sp8)
{
  const int nb = blockIdx.x * 64;
  const int cb = blockIdx.y * 64;
  const int b  = blockIdx.z;
  const int n  = threadIdx.x & 63;
  const int c0 = (threadIdx.x >> 6) * 16;
  unsigned char sp[4][16];
#pragma unroll
  for (int j = 0; j < 16; ++j) {
    int c = cb + c0 + j;
    float v = 0.f;
#pragma unroll
    for (int t = 0; t < T_; ++t) {
      float a = 0.125f * (float)A16[((size_t)(t * B_ + b) * C_ + c) * N_ + nb + n];
      v = (v + a) * 0.5f;
      bool s = (v >= 0.5f);
      sp[t][j] = s ? 1 : 0;
      if (s) v = 0.f;
    }
  }
#pragma unroll
  for (int t = 0; t < T_; ++t) {
    unsigned w[4];
#pragma unroll
    for (int q = 0; q < 4; ++q)
      w[q] = (unsigned)sp[t][4*q+0] | ((unsigned)sp[t][4*q+1] << 8)
           | ((unsigned)sp[t][4*q+2] << 16) | ((unsigned)sp[t][4*q+3] << 24);
    uint4 u; u.x = w[0]; u.y = w[1]; u.z = w[2]; u.w = w[3];
    *reinterpret_cast<uint4*>(
        &Sp8[((size_t)(t * B_ + b) * N_ + nb + n) * C_ + cb + c0]) = u;
  }
}

// BN-normalize + 4-step LIF (stats finalized inline from partials).
__global__ __launch_bounds__(256) void bn_lif_bits(
    const double* __restrict__ Y, const double* __restrict__ part,
    const float* __restrict__ gamma, const float* __restrict__ beta,
    double vth, u64* __restrict__ bits)
{
  const int o = blockIdx.x & (C_ - 1);
  const int b = blockIdx.x >> 9;
  const int n = threadIdx.x;
  double mu, rsig;
  stats_from_part(part, o, mu, rsig);
  const double g = (double)gamma[o], be = (double)beta[o];
  double v = 0.0;
#pragma unroll
  for (int t = 0; t < T_; ++t) {
    double y  = Y[((size_t)(t * B_ + b) * C_ + o) * N_ + n];
    double yn = (y - mu) * rsig * g + be;
    v = v + (yn - v) * 0.5;
    bool sp = (v >= vth);
    u64 m = __ballot(sp);
    if ((n & 63) == 0)
      bits[((size_t)(t * B_ + b) * C_ + o) * (N_ / 64) + (n >> 6)] = m;
    if (sp) v = 0.0;
  }
}

__global__ __launch_bounds__(256) void bn_lif_out(
    const double* __restrict__ Y, const double* __restrict__ part,
    const float* __restrict__ gamma, const float* __restrict__ beta,
    float* __restrict__ out)
{
  const int o = blockIdx.x & (C_ - 1);
  const int b = blockIdx.x >> 9;
  const int n = threadIdx.x;
  double mu, rsig;
  stats_from_part(part, o, mu, rsig);
  const double g = (double)gamma[o], be = (double)beta[o];
  double v = 0.0;
#pragma unroll
  for (int t = 0; t < T_; ++t) {
    double y  = Y[((size_t)(t * B_ + b) * C_ + o) * N_ + n];
    double yn = (y - mu) * rsig * g + be;
    v = v + (yn - v) * 0.5;
    bool sp = (v >= 1.0);
    out[((size_t)(t * B_ + b) * C_ + o) * N_ + n] = sp ? 1.0f : 0.0f;
    if (sp) v = 0.0;
  }
}

// ===================== FALLBACK (R4, proven) kernels ========================

__global__ __launch_bounds__(128) void decomp_w(
    const float* __restrict__ W, char* __restrict__ Wsl)
{
  const int o = blockIdx.x;
  const int k4 = threadIdx.x * 4;
  float4 w4 = *reinterpret_cast<const float4*>(&W[(size_t)o * C_ + k4]);
  int d[4][6];
  digitize6(w4.x, 0x1p47, d[0]);
  digitize6(w4.y, 0x1p47, d[1]);
  digitize6(w4.z, 0x1p47, d[2]);
  digitize6(w4.w, 0x1p47, d[3]);
#pragma unroll
  for (int s = 0; s < 6; ++s) {
    unsigned u = (unsigned)(d[0][s] & 255) | ((unsigned)(d[1][s] & 255) << 8)
               | ((unsigned)(d[2][s] & 255) << 16) | ((unsigned)(d[3][s] & 255) << 24);
    *reinterpret_cast<unsigned*>(&Wsl[(size_t)s * C_ * C_ + (size_t)o * C_ + k4]) = u;
  }
}

template<int XS>
__global__ __launch_bounds__(256) void gemm_i8(
    const float* __restrict__ X, const char* __restrict__ Wsl,
    double* __restrict__ Y)
{
  __shared__ char Xs[XS][64][72];
  const int tb = blockIdx.z;
  const int ob = blockIdx.y * 64;
  const int nb = blockIdx.x * 64;
  const int tid = threadIdx.x;
  const int lane = tid & 63;
  const int wv = tid >> 6;
  const int wo = (wv & 1) * 32;
  const int wn = (wv >> 1) * 32;
  const int lr = lane & 15;
  const int lg = lane >> 4;

  constexpr int NU = (XS == 6) ? 7 : 6;
  v4i acc[NU][2][2] = {};

  const int sn = tid & 63;
  const int kq = (tid >> 6) * 4;

  for (int cb = 0; cb < C_; cb += 64) {
    __syncthreads();
#pragma unroll
    for (int st = 0; st < 4; ++st) {
      int k0 = kq + 16 * st;
      int dg[4][6];
#pragma unroll
      for (int j = 0; j < 4; ++j) {
        float xv = X[((size_t)tb * C_ + cb + k0 + j) * N_ + nb + sn];
        digitize6(xv, 0x1p43, dg[j]);
      }
#pragma unroll
      for (int t = 0; t < XS; ++t) {
        unsigned u = (unsigned)(dg[0][t] & 255) | ((unsigned)(dg[1][t] & 255) << 8)
                   | ((unsigned)(dg[2][t] & 255) << 16) | ((unsigned)(dg[3][t] & 255) << 24);
        *reinterpret_cast<unsigned*>(&Xs[t][sn][k0]) = u;
      }
    }
    __syncthreads();

    v4i Bf[XS][2];
#pragma unroll
    for (int t = 0; t < XS; ++t)
#pragma unroll
      for (int nt = 0; nt < 2; ++nt) {
        const char* p = &Xs[t][wn + nt * 16 + lr][lg * 16];
        int2 lo = *reinterpret_cast<const int2*>(p);
        int2 hi = *reinterpret_cast<const int2*>(p + 8);
        v4i b; b[0] = lo.x; b[1] = lo.y; b[2] = hi.x; b[3] = hi.y;
        Bf[t][nt] = b;
      }

#pragma unroll
    for (int s = 0; s < 6; ++s) {
      v4i Af[2];
#pragma unroll
      for (int ot = 0; ot < 2; ++ot) {
        const char* ap = Wsl + (size_t)s * C_ * C_
                       + (size_t)(ob + wo + ot * 16 + lr) * C_ + cb + lg * 16;
        Af[ot] = *reinterpret_cast<const v4i*>(ap);
      }
#pragma unroll
      for (int t = 0; t < XS; ++t) {
        if (s + t <= 6) {
#pragma unroll
          for (int ot = 0; ot < 2; ++ot)
#pragma unroll
            for (int nt = 0; nt < 2; ++nt)
              acc[s + t][ot][nt] = __builtin_amdgcn_mfma_i32_16x16x64_i8(
                  Af[ot], Bf[t][nt], acc[s + t][ot][nt], 0, 0, 0);
        }
      }
    }
  }

  const double WGT[7] = {0x1p-10, 0x1p-18, 0x1p-26, 0x1p-34,
                         0x1p-42, 0x1p-50, 0x1p-58};
#pragma unroll
  for (int ot = 0; ot < 2; ++ot)
#pragma unroll
    for (int nt = 0; nt < 2; ++nt)
#pragma unroll
      for (int r = 0; r < 4; ++r) {
        double y = 0.0;
#pragma unroll
        for (int u = 0; u < NU; ++u)
          y = fma((double)acc[u][ot][nt][r], WGT[u], y);
        int o = ob + wo + ot * 16 + lg * 4 + r;
        int n = nb + wn + nt * 16 + lr;
        Y[((size_t)tb * C_ + o) * N_ + n] = y;
      }
}

__global__ __launch_bounds__(256) void attn_kernel(
    const u64* __restrict__ qb, const u64* __restrict__ kb,
    const u64* __restrict__ vb, float* __restrict__ A)
{
  __shared__ u64 kw[64][4], vw[64][4], qw[64][4];
  __shared__ int kvs[64][64];
  const int h  = blockIdx.x & 7;
  const int tb = blockIdx.x >> 3;
  const int tid = threadIdx.x;
  {
    int dd = tid >> 2, w = tid & 3;
    size_t base = ((size_t)tb * C_ + h * 64 + dd) * 4 + w;
    kw[dd][w] = kb[base];
    vw[dd][w] = vb[base];
    qw[dd][w] = qb[base];
  }
  __syncthreads();
  {
    int dd = tid >> 2;
    int e0 = (tid & 3) << 4;
    u64 k0 = kw[dd][0], k1 = kw[dd][1], k2 = kw[dd][2], k3 = kw[dd][3];
    for (int e = e0; e < e0 + 16; ++e) {
      int c = __popcll(k0 & vw[e][0]) + __popcll(k1 & vw[e][1])
            + __popcll(k2 & vw[e][2]) + __popcll(k3 & vw[e][3]);
      kvs[dd][e] = c;
    }
  }
  __syncthreads();
  const int n = tid;
  u64 qmask = 0;
  {
    int wsel = n >> 6, sh = n & 63;
#pragma unroll
    for (int dd = 0; dd < 64; ++dd)
      qmask |= ((qw[dd][wsel] >> sh) & 1ull) << dd;
  }
  float* Ap = A + ((size_t)tb * C_ + h * 64) * N_ + n;
  for (int e = 0; e < 64; ++e) {
    int s = 0;
#pragma unroll
    for (int dd = 0; dd < 64; ++dd) {
      int m = -(int)((qmask >> dd) & 1ull);
      s += kvs[dd][e] & m;
    }
    Ap[(size_t)e * N_] = (float)s * 0.125f;
  }
}

__global__ __launch_bounds__(256) void attn_lif(float* __restrict__ A)
{
  const size_t i = (size_t)blockIdx.x * 256 + threadIdx.x;
  const size_t stride = (size_t)B_ * C_ * N_;
  float v = 0.f;
#pragma unroll
  for (int t = 0; t < T_; ++t) {
    float a = A[t * stride + i];
    v = v + (a - v) * 0.5f;
    bool sp = (v >= 0.5f);
    A[t * stride + i] = sp ? 1.0f : 0.0f;
    if (sp) v = 0.f;
  }
}

__global__ __launch_bounds__(256) void bn_stats(
    const double* __restrict__ Y, double* __restrict__ stats)
{
  const int o = blockIdx.x;
  const int n = threadIdx.x;
  double s = 0.0, s2 = 0.0;
  for (int tb = 0; tb < TB_; ++tb) {
    double v = Y[((size_t)tb * C_ + o) * N_ + n];
    s += v;
    s2 = fma(v, v, s2);
  }
  __shared__ double rs[256], rq[256];
  rs[n] = s; rq[n] = s2;
  __syncthreads();
  for (int off = 128; off > 0; off >>= 1) {
    if (n < off) { rs[n] += rs[n + off]; rq[n] += rq[n + off]; }
    __syncthreads();
  }
  if (n == 0) {
    double mu  = rs[0] * (1.0 / 16384.0);
    double var = rq[0] * (1.0 / 16384.0) - mu * mu;
    stats[o]      = mu;
    stats[C_ + o] = 1.0 / sqrt(var + 1e-5);
  }
}

__global__ __launch_bounds__(256) void bn_lif_bits_fb(
    const double* __restrict__ Y, const double* __restrict__ stats,
    const float* __restrict__ gamma, const float* __restrict__ beta,
    double vth, u64* __restrict__ bits)
{
  const int o = blockIdx.x & (C_ - 1);
  const int b = blockIdx.x >> 9;
  const int n = threadIdx.x;
  const double mu = stats[o], rsig = stats[C_ + o];
  const double g = (double)gamma[o], be = (double)beta[o];
  double v = 0.0;
#pragma unroll
  for (int t = 0; t < T_; ++t) {
    double y  = Y[((size_t)(t * B_ + b) * C_ + o) * N_ + n];
    double yn = (y - mu) * rsig * g + be;
    v = v + (yn - v) * 0.5;
    bool sp = (v >= vth);
    u64 m = __ballot(sp);
    if ((n & 63) == 0)
      bits[((size_t)(t * B_ + b) * C_ + o) * (N_ / 64) + (n >> 6)] = m;
    if (sp) v = 0.0;
  }
}

__global__ __launch_bounds__(256) void bn_lif_out_fb(
    const double* __restrict__ Y, const double* __restrict__ stats,
    const float* __restrict__ gamma, const float* __restrict__ beta,
    float* __restrict__ out)
{
  const int o = blockIdx.x & (C_ - 1);
  const int b = blockIdx.x >> 9;
  const int n = threadIdx.x;
  const double mu = stats[o], rsig = stats[C_ + o];
  const double g = (double)gamma[o], be = (double)beta[o];
  double v = 0.0;
#pragma unroll
  for (int t = 0; t < T_; ++t) {
    double y  = Y[((size_t)(t * B_ + b) * C_ + o) * N_ + n];
    double yn = (y - mu) * rsig * g + be;
    v = v + (yn - v) * 0.5;
    bool sp = (v >= 1.0);
    out[((size_t)(t * B_ + b) * C_ + o) * N_ + n] = sp ? 1.0f : 0.0f;
    if (sp) v = 0.0;
  }
}

// ---------------------------------------------------------------------------
extern "C" void kernel_launch(void* const* d_in, const int* in_sizes, int n_in,
                              void* d_out, int out_size, void* d_ws, size_t ws_size,
                              hipStream_t stream)
{
  const float* x    = (const float*)d_in[0];
  const float* qW   = (const float*)d_in[1];
  const float* qg   = (const float*)d_in[2];
  const float* qbt  = (const float*)d_in[3];
  const float* kW   = (const float*)d_in[4];
  const float* kg   = (const float*)d_in[5];
  const float* kbt  = (const float*)d_in[6];
  const float* vW   = (const float*)d_in[7];
  const float* vg   = (const float*)d_in[8];
  const float* vbt  = (const float*)d_in[9];
  const float* pW   = (const float*)d_in[10];
  // d_in[11] proj_b cancels exactly under BN mean subtraction -> unused
  const float* pg   = (const float*)d_in[12];
  const float* pbt  = (const float*)d_in[13];

  char* ws = (char*)d_ws;
  double* yD    = (double*)ws;                    // 67,108,864 B
  u64*    bitsQ = (u64*)(ws + 100663296);         //  1,048,576 B
  u64*    bitsK = (u64*)(ws + 101711872);         //  1,048,576 B
  u64*    bitsV = (u64*)(ws + 102760448);         //  1,048,576 B
  double* stats = (double*)(ws + 103809024);      //      8,192 B

  if (ws_size >= 105390080ull) {
    // ---------------- fast path: pre-digitized operand planes ----------------
    char*   Xd4  = ws + 67108864;                 // 33,554,432 B (dead after V)
    short*  A16  = (short*)(ws + 67108864);       // 16,777,216 B (after V gemm)
    char*   Sp8  = ws + 67108864 + 16777216;      //  8,388,608 B
    char*   Wsl5 = ws + 103817216;                //  1,310,720 B
    double* part = (double*)(ws + 105127936);     //     65,536 B

    dim3 ggrid(4, 8, 64);

    predig_x<<<dim3(8, 4, 64), 256, 0, stream>>>(x, Xd4);
    // Q
    decomp_w5i<<<512, 128, 0, stream>>>(qW, Wsl5);
    gemm_s<4><<<ggrid, 256, 0, stream>>>(Xd4, Wsl5, yD);
    bn_stats_part<<<4096, 256, 0, stream>>>(yD, part);
    bn_lif_bits<<<8192, 256, 0, stream>>>(yD, part, qg, qbt, 1.0, bitsQ);
    // K
    decomp_w5i<<<512, 128, 0, stream>>>(kW, Wsl5);
    gemm_s<4><<<ggrid, 256, 0, stream>>>(Xd4, Wsl5, yD);
    bn_stats_part<<<4096, 256, 0, stream>>>(yD, part);
    bn_lif_bits<<<8192, 256, 0, stream>>>(yD, part, kg, kbt, 1.0, bitsK);
    // V
    decomp_w5i<<<512, 128, 0, stream>>>(vW, Wsl5);
    gemm_s<4><<<ggrid, 256, 0, stream>>>(Xd4, Wsl5, yD);
    bn_stats_part<<<4096, 256, 0, stream>>>(yD, part);
    bn_lif_bits<<<8192, 256, 0, stream>>>(yD, part, vg, vbt, 1.0, bitsV);
    // attention (exact int) + LIF -> transposed binary i8 (overwrites Xd4)
    attn16<<<512, 256, 0, stream>>>(bitsQ, bitsK, bitsV, A16);
    attn_lif_sp<<<dim3(4, 8, 16), 256, 0, stream>>>(A16, Sp8);
    // projection (binary B, 5 w-digits)
    decomp_w5i<<<512, 128, 0, stream>>>(pW, Wsl5);
    gemm_s<1><<<ggrid, 256, 0, stream>>>(Sp8, Wsl5, yD);
    bn_stats_part<<<4096, 256, 0, stream>>>(yD, part);
    bn_lif_out<<<8192, 256, 0, stream>>>(yD, part, pg, pbt, (float*)d_out);
  } else {
    // ---------------- fallback: proven R4 pipeline ----------------
    float* A    = (float*)(ws + 67108864);
    char*  WslA = ws + 67108864;
    char*  WslB = ws + 100663296;

    dim3 ggrid(4, 8, 64);

    decomp_w<<<512, 128, 0, stream>>>(qW, WslA);
    gemm_i8<6><<<ggrid, 256, 0, stream>>>(x, WslA, yD);
    bn_stats<<<512, 256, 0, stream>>>(yD, stats);
    bn_lif_bits_fb<<<8192, 256, 0, stream>>>(yD, stats, qg, qbt, 1.0, bitsQ);
    decomp_w<<<512, 128, 0, stream>>>(kW, WslA);
    gemm_i8<6><<<ggrid, 256, 0, stream>>>(x, WslA, yD);
    bn_stats<<<512, 256, 0, stream>>>(yD, stats);
    bn_lif_bits_fb<<<8192, 256, 0, stream>>>(yD, stats, kg, kbt, 1.0, bitsK);
    decomp_w<<<512, 128, 0, stream>>>(vW, WslA);
    gemm_i8<6><<<ggrid, 256, 0, stream>>>(x, WslA, yD);
    bn_stats<<<512, 256, 0, stream>>>(yD, stats);
    bn_lif_bits_fb<<<8192, 256, 0, stream>>>(yD, stats, vg, vbt, 1.0, bitsV);
    attn_kernel<<<512, 256, 0, stream>>>(bitsQ, bitsK, bitsV, A);
    attn_lif<<<8192, 256, 0, stream>>>(A);
    decomp_w<<<512, 128, 0, stream>>>(pW, WslB);
    gemm_i8<1><<<ggrid, 256, 0, stream>>>(A, WslB, yD);
    bn_stats<<<512, 256, 0, stream>>>(yD, stats);
    bn_lif_out_fb<<<8192, 256, 0, stream>>>(yD, stats, pg, pbt, (float*)d_out);
  }
}

// Round 21
// 396.183 us; speedup vs baseline: 2.0686x; 1.0300x over previous
//
#include <hip/hip_runtime.h>

#define T_ 4
#define B_ 16
#define C_ 512
#define N_ 256
#define TB_ 64

using u64 = unsigned long long;
typedef int v4i __attribute__((ext_vector_type(4)));

// ============================ shared helpers ================================

__device__ __forceinline__ void digitize6(float xf, double scale, int d[6]) {
  double m = (double)xf * scale;
  long long t = (long long)rint(m);
#pragma unroll
  for (int s = 5; s >= 0; --s) {
    int dig = (int)((t + 128) & 255) - 128;
    d[s] = dig;
    t = (t - dig) >> 8;
  }
}

__device__ __forceinline__ void digitize5(float xf, double scale, int d[5]) {
  double m = (double)xf * scale;
  long long t = (long long)rint(m);
#pragma unroll
  for (int s = 4; s >= 0; --s) {
    int dig = (int)((t + 128) & 255) - 128;
    d[s] = dig;
    t = (t - dig) >> 8;
  }
}

// 4-digit balanced base-256, S=2^28 (span +-8; exact for |x|>=2^-5 fp32).
__device__ __forceinline__ void dig4(float xv, int d[4]) {
  float c = fminf(fmaxf(xv, -7.999999f), 7.999999f);
  int m = (int)rintf(c * 268435456.0f);
#pragma unroll
  for (int t = 3; t >= 0; --t) {
    int dd = ((m + 128) & 255) - 128;
    d[t] = dd;
    m = (m - dd) >> 8;
  }
}

// async global->LDS, 16B per lane. LDS dest = wave-uniform base + lane*16.
__device__ __forceinline__ void gload16(const void* g, void* l) {
  __builtin_amdgcn_global_load_lds(
      (const __attribute__((address_space(1))) unsigned int*)(unsigned long long)g,
      (__attribute__((address_space(3))) unsigned int*)(unsigned long long)l,
      16, 0, 0);
}

// ===================== STORED-PLANE FAST PATH kernels =======================

// X [TB][C][N] f32 -> Xd4 [tb][n][4t][512c] i8 (transposed, MFMA-ready rows)
__global__ __launch_bounds__(256) void predig_x(
    const float* __restrict__ X, char* __restrict__ Xd4)
{
  const int cb = blockIdx.x * 64;
  const int nb = blockIdx.y * 64;
  const int tb = blockIdx.z;
  const int n  = threadIdx.x & 63;
  const int c0 = (threadIdx.x >> 6) * 16;
  int dg[16][4];
#pragma unroll
  for (int j = 0; j < 16; ++j) {
    float xv = X[((size_t)tb * C_ + cb + c0 + j) * N_ + nb + n];
    dig4(xv, dg[j]);
  }
#pragma unroll
  for (int t = 0; t < 4; ++t) {
    unsigned w[4];
#pragma unroll
    for (int q = 0; q < 4; ++q)
      w[q] = (unsigned)(dg[4*q+0][t] & 255)
           | ((unsigned)(dg[4*q+1][t] & 255) << 8)
           | ((unsigned)(dg[4*q+2][t] & 255) << 16)
           | ((unsigned)(dg[4*q+3][t] & 255) << 24);
    uint4 u; u.x = w[0]; u.y = w[1]; u.z = w[2]; u.w = w[3];
    *reinterpret_cast<uint4*>(
        &Xd4[(((size_t)tb * N_ + nb + n) * 4 + t) * C_ + cb + c0]) = u;
  }
}

// W [o][c] f32 -> Wsl [o][5s][512c] i8 interleaved, scale 2^39.
__global__ __launch_bounds__(128) void decomp_w5i(
    const float* __restrict__ W, char* __restrict__ Wsl)
{
  const int o = blockIdx.x;
  const int k4 = threadIdx.x * 4;
  float4 w4 = *reinterpret_cast<const float4*>(&W[(size_t)o * C_ + k4]);
  int d[4][5];
  digitize5(w4.x, 0x1p39, d[0]);
  digitize5(w4.y, 0x1p39, d[1]);
  digitize5(w4.z, 0x1p39, d[2]);
  digitize5(w4.w, 0x1p39, d[3]);
#pragma unroll
  for (int s = 0; s < 5; ++s) {
    unsigned u = (unsigned)(d[0][s] & 255) | ((unsigned)(d[1][s] & 255) << 8)
               | ((unsigned)(d[2][s] & 255) << 16) | ((unsigned)(d[3][s] & 255) << 24);
    *reinterpret_cast<unsigned*>(&Wsl[((size_t)o * 5 + s) * C_ + k4]) = u;
  }
}

// GEMM on pre-digitized planes — R20-proven dual global_load_lds staging
// (zero vmcnt waits in compute chain) + FUSED BN STATS (R12-validated
// integer-atomic scheme, lean 8-atomics/wave epilogue): sum(y)@2^-40,
// sum(y^2)@2^-35 into istats[o] / istats[C+o] (order-independent u64
// atomics -> deterministic). istats must be zeroed before launch.
// MFMA chain and Y values identical to R20 -> Y bit-identical.
// XP=4: B = Xd4 [tb][n][4][512], 14 pairs (s+t<=4), W0 = 2^-11
// XP=1: B = Sp8 [tb][n][512] binary, 5 pairs,        W0 = 2^-7
template<int XP>
__global__ __launch_bounds__(256) void gemm_s(
    const char* __restrict__ Bp, const char* __restrict__ Wsl,
    double* __restrict__ Y, u64* __restrict__ istats)
{
  __shared__ v4i Als[2][5][64][4];    // [buf][s][o][slot] 40KB
  __shared__ v4i Bls[2][XP][64][4];   // [buf][t][n][slot] 32KB/8KB
  const int tb = blockIdx.z;
  const int ob = blockIdx.y * 64;
  const int nb = blockIdx.x * 64;
  const int tid = threadIdx.x;
  const int lane = tid & 63;
  const int wv = tid >> 6;          // 0..3
  const int wo = wv * 16;           // wave o-offset
  const int lr = lane & 15;
  const int lg = lane >> 4;

  v4i acc[5][4] = {};   // [u][nt] — 80 regs

  // ---- A staging geometry (R20-proven)
  const int sow = wv * 16 + (lane >> 2);
  const int acs = (lane & 3) ^ ((sow >> 1) & 3);
  const char* asrc[5];
#pragma unroll
  for (int s = 0; s < 5; ++s)
    asrc[s] = Wsl + ((size_t)(ob + sow) * 5 + s) * C_ + acs * 16;

  // ---- B staging geometry (R15/R19/R20-proven)
  const int s_slot = lane & 3;
  const char* bsrc[(XP == 4) ? 4 : 1];
  if (XP == 4) {
#pragma unroll
    for (int r = 0; r < 4; ++r) {
      int sn = r * 16 + (lane >> 2);
      bsrc[r] = Bp + (((size_t)tb * N_ + nb + sn) * 4 + wv) * C_
              + ((s_slot ^ ((sn >> 1) & 3)) * 16);
    }
  } else {
    int sn = wv * 16 + (lane >> 2);
    bsrc[0] = Bp + ((size_t)tb * N_ + nb + sn) * C_
            + ((s_slot ^ ((sn >> 1) & 3)) * 16);
  }

#define STAGE_(buf, cb) do {                                              \
    _Pragma("unroll")                                                     \
    for (int s_ = 0; s_ < 5; ++s_)                                        \
      gload16(asrc[s_] + (cb), &Als[buf][s_][wv * 16][0]);                \
    if (XP == 4) {                                                        \
      _Pragma("unroll")                                                   \
      for (int r_ = 0; r_ < 4; ++r_)                                      \
        gload16(bsrc[r_] + (cb), &Bls[buf][wv][r_ * 16][0]);              \
    } else {                                                              \
      gload16(bsrc[0] + (cb), &Bls[buf][0][wv * 16][0]);                  \
    }                                                                     \
  } while (0)

  // prologue: stage chunk 0 into buf 0 (syncthreads drains vmcnt)
  STAGE_(0, 0);
  __syncthreads();

#pragma unroll
  for (int i = 0; i < 8; ++i) {
    const int cur = i & 1;
    const int cb = i * 64;
    if (i < 7) STAGE_(cur ^ 1, cb + 64);
    __builtin_amdgcn_sched_barrier(0);
    v4i Af[5];
#pragma unroll
    for (int s = 0; s < 5; ++s) {
      const int o = wo + lr;
      Af[s] = Als[cur][s][o][lg ^ ((o >> 1) & 3)];
    }
    v4i Bf[XP][4];
#pragma unroll
    for (int t = 0; t < XP; ++t)
#pragma unroll
      for (int nt = 0; nt < 4; ++nt) {
        const int n = nt * 16 + lr;
        Bf[t][nt] = Bls[cur][t][n][lg ^ ((n >> 1) & 3)];
      }
#pragma unroll
    for (int s = 0; s < 5; ++s)
#pragma unroll
      for (int t = 0; t < XP; ++t) {
        if (s + t <= 4) {
#pragma unroll
          for (int nt = 0; nt < 4; ++nt)
            acc[s + t][nt] = __builtin_amdgcn_mfma_i32_16x16x64_i8(
                Af[s], Bf[t][nt], acc[s + t][nt], 0, 0, 0);
        }
      }
    if (i < 7) __syncthreads();
  }
#undef STAGE_

  // epilogue: Y values (identical to R20) + fused integer-quantized stats
  const double W0 = (XP == 4) ? 0x1p-11 : 0x1p-7;
  double ys[4][4];
#pragma unroll
  for (int nt = 0; nt < 4; ++nt)
#pragma unroll
    for (int r = 0; r < 4; ++r) {
      double y = 0.0;
      double wgt = W0;
#pragma unroll
      for (int u = 0; u < 5; ++u) {
        y = fma((double)acc[u][nt][r], wgt, y);
        wgt *= 0x1p-8;
      }
      ys[nt][r] = y;
      int o = ob + wo + lg * 4 + r;
      int n = nb + nt * 16 + lr;
      Y[((size_t)tb * C_ + o) * N_ + n] = y;
    }
#pragma unroll
  for (int r = 0; r < 4; ++r) {
    double s = ys[0][r] + ys[1][r] + ys[2][r] + ys[3][r];
    double q = ys[0][r] * ys[0][r] + ys[1][r] * ys[1][r]
             + ys[2][r] * ys[2][r] + ys[3][r] * ys[3][r];
#pragma unroll
    for (int m = 1; m < 16; m <<= 1) {
      s += __shfl_xor(s, m, 64);
      q += __shfl_xor(q, m, 64);
    }
    if (lr == 0) {
      int o = ob + wo + lg * 4 + r;
      atomicAdd(&istats[o],      (u64)(long long)llrint(s * 0x1p40));
      atomicAdd(&istats[C_ + o], (u64)llrint(q * 0x1p35));
    }
  }
}

// Attention producing i16 counts (a = 0.125 * count applied later).
__global__ __launch_bounds__(256) void attn16(
    const u64* __restrict__ qb, const u64* __restrict__ kb,
    const u64* __restrict__ vb, short* __restrict__ A16)
{
  __shared__ u64 kw[64][4], vw[64][4], qw[64][4];
  __shared__ int kvs[64][64];
  const int h  = blockIdx.x & 7;
  const int tb = blockIdx.x >> 3;
  const int tid = threadIdx.x;
  {
    int dd = tid >> 2, w = tid & 3;
    size_t base = ((size_t)tb * C_ + h * 64 + dd) * 4 + w;
    kw[dd][w] = kb[base];
    vw[dd][w] = vb[base];
    qw[dd][w] = qb[base];
  }
  __syncthreads();
  {
    int dd = tid >> 2;
    int e0 = (tid & 3) << 4;
    u64 k0 = kw[dd][0], k1 = kw[dd][1], k2 = kw[dd][2], k3 = kw[dd][3];
    for (int e = e0; e < e0 + 16; ++e) {
      int c = __popcll(k0 & vw[e][0]) + __popcll(k1 & vw[e][1])
            + __popcll(k2 & vw[e][2]) + __popcll(k3 & vw[e][3]);
      kvs[dd][e] = c;
    }
  }
  __syncthreads();
  const int n = tid;
  u64 qmask = 0;
  {
    int wsel = n >> 6, sh = n & 63;
#pragma unroll
    for (int dd = 0; dd < 64; ++dd)
      qmask |= ((qw[dd][wsel] >> sh) & 1ull) << dd;
  }
  short* Ap = A16 + ((size_t)tb * C_ + h * 64) * N_ + n;
  for (int e = 0; e < 64; ++e) {
    int s = 0;
#pragma unroll
    for (int dd = 0; dd < 64; ++dd) {
      int m = -(int)((qmask >> dd) & 1ull);
      s += kvs[dd][e] & m;
    }
    Ap[(size_t)e * N_] = (short)s;
  }
}

// attn LIF (vth=0.5, exact fp32 on dyadics) -> binary i8 spikes transposed
// Sp8 [tb][n][512c].
__global__ __launch_bounds__(256) void attn_lif_sp(
    const short* __restrict__ A16, char* __restrict__ Sp8)
{
  const int nb = blockIdx.x * 64;
  const int cb = blockIdx.y * 64;
  const int b  = blockIdx.z;
  const int n  = threadIdx.x & 63;
  const int c0 = (threadIdx.x >> 6) * 16;
  unsigned char sp[4][16];
#pragma unroll
  for (int j = 0; j < 16; ++j) {
    int c = cb + c0 + j;
    float v = 0.f;
#pragma unroll
    for (int t = 0; t < T_; ++t) {
      float a = 0.125f * (float)A16[((size_t)(t * B_ + b) * C_ + c) * N_ + nb + n];
      v = (v + a) * 0.5f;
      bool s = (v >= 0.5f);
      sp[t][j] = s ? 1 : 0;
      if (s) v = 0.f;
    }
  }
#pragma unroll
  for (int t = 0; t < T_; ++t) {
    unsigned w[4];
#pragma unroll
    for (int q = 0; q < 4; ++q)
      w[q] = (unsigned)sp[t][4*q+0] | ((unsigned)sp[t][4*q+1] << 8)
           | ((unsigned)sp[t][4*q+2] << 16) | ((unsigned)sp[t][4*q+3] << 24);
    uint4 u; u.x = w[0]; u.y = w[1]; u.z = w[2]; u.w = w[3];
    *reinterpret_cast<uint4*>(
        &Sp8[((size_t)(t * B_ + b) * N_ + nb + n) * C_ + cb + c0]) = u;
  }
}

// BN-normalize + 4-step LIF from integer stats (R12-validated), bit-packed.
__global__ __launch_bounds__(256) void bn_lif_bits(
    const double* __restrict__ Y, const u64* __restrict__ istats,
    const float* __restrict__ gamma, const float* __restrict__ beta,
    double vth, u64* __restrict__ bits)
{
  const int o = blockIdx.x & (C_ - 1);
  const int b = blockIdx.x >> 9;
  const int n = threadIdx.x;
  const double mu  = (double)(long long)istats[o] * 0x1p-54;
  const double ex2 = (double)istats[C_ + o] * 0x1p-49;
  const double rsig = 1.0 / sqrt(ex2 - mu * mu + 1e-5);
  const double g = (double)gamma[o], be = (double)beta[o];
  double v = 0.0;
#pragma unroll
  for (int t = 0; t < T_; ++t) {
    double y  = Y[((size_t)(t * B_ + b) * C_ + o) * N_ + n];
    double yn = (y - mu) * rsig * g + be;
    v = v + (yn - v) * 0.5;
    bool sp = (v >= vth);
    u64 m = __ballot(sp);
    if ((n & 63) == 0)
      bits[((size_t)(t * B_ + b) * C_ + o) * (N_ / 64) + (n >> 6)] = m;
    if (sp) v = 0.0;
  }
}

__global__ __launch_bounds__(256) void bn_lif_out(
    const double* __restrict__ Y, const u64* __restrict__ istats,
    const float* __restrict__ gamma, const float* __restrict__ beta,
    float* __restrict__ out)
{
  const int o = blockIdx.x & (C_ - 1);
  const int b = blockIdx.x >> 9;
  const int n = threadIdx.x;
  const double mu  = (double)(long long)istats[o] * 0x1p-54;
  const double ex2 = (double)istats[C_ + o] * 0x1p-49;
  const double rsig = 1.0 / sqrt(ex2 - mu * mu + 1e-5);
  const double g = (double)gamma[o], be = (double)beta[o];
  double v = 0.0;
#pragma unroll
  for (int t = 0; t < T_; ++t) {
    double y  = Y[((size_t)(t * B_ + b) * C_ + o) * N_ + n];
    double yn = (y - mu) * rsig * g + be;
    v = v + (yn - v) * 0.5;
    bool sp = (v >= 1.0);
    out[((size_t)(t * B_ + b) * C_ + o) * N_ + n] = sp ? 1.0f : 0.0f;
    if (sp) v = 0.0;
  }
}

// ===================== FALLBACK (R4, proven) kernels ========================

__global__ __launch_bounds__(128) void decomp_w(
    const float* __restrict__ W, char* __restrict__ Wsl)
{
  const int o = blockIdx.x;
  const int k4 = threadIdx.x * 4;
  float4 w4 = *reinterpret_cast<const float4*>(&W[(size_t)o * C_ + k4]);
  int d[4][6];
  digitize6(w4.x, 0x1p47, d[0]);
  digitize6(w4.y, 0x1p47, d[1]);
  digitize6(w4.z, 0x1p47, d[2]);
  digitize6(w4.w, 0x1p47, d[3]);
#pragma unroll
  for (int s = 0; s < 6; ++s) {
    unsigned u = (unsigned)(d[0][s] & 255) | ((unsigned)(d[1][s] & 255) << 8)
               | ((unsigned)(d[2][s] & 255) << 16) | ((unsigned)(d[3][s] & 255) << 24);
    *reinterpret_cast<unsigned*>(&Wsl[(size_t)s * C_ * C_ + (size_t)o * C_ + k4]) = u;
  }
}

template<int XS>
__global__ __launch_bounds__(256) void gemm_i8(
    const float* __restrict__ X, const char* __restrict__ Wsl,
    double* __restrict__ Y)
{
  __shared__ char Xs[XS][64][72];
  const int tb = blockIdx.z;
  const int ob = blockIdx.y * 64;
  const int nb = blockIdx.x * 64;
  const int tid = threadIdx.x;
  const int lane = tid & 63;
  const int wv = tid >> 6;
  const int wo = (wv & 1) * 32;
  const int wn = (wv >> 1) * 32;
  const int lr = lane & 15;
  const int lg = lane >> 4;

  constexpr int NU = (XS == 6) ? 7 : 6;
  v4i acc[NU][2][2] = {};

  const int sn = tid & 63;
  const int kq = (tid >> 6) * 4;

  for (int cb = 0; cb < C_; cb += 64) {
    __syncthreads();
#pragma unroll
    for (int st = 0; st < 4; ++st) {
      int k0 = kq + 16 * st;
      int dg[4][6];
#pragma unroll
      for (int j = 0; j < 4; ++j) {
        float xv = X[((size_t)tb * C_ + cb + k0 + j) * N_ + nb + sn];
        digitize6(xv, 0x1p43, dg[j]);
      }
#pragma unroll
      for (int t = 0; t < XS; ++t) {
        unsigned u = (unsigned)(dg[0][t] & 255) | ((unsigned)(dg[1][t] & 255) << 8)
                   | ((unsigned)(dg[2][t] & 255) << 16) | ((unsigned)(dg[3][t] & 255) << 24);
        *reinterpret_cast<unsigned*>(&Xs[t][sn][k0]) = u;
      }
    }
    __syncthreads();

    v4i Bf[XS][2];
#pragma unroll
    for (int t = 0; t < XS; ++t)
#pragma unroll
      for (int nt = 0; nt < 2; ++nt) {
        const char* p = &Xs[t][wn + nt * 16 + lr][lg * 16];
        int2 lo = *reinterpret_cast<const int2*>(p);
        int2 hi = *reinterpret_cast<const int2*>(p + 8);
        v4i b; b[0] = lo.x; b[1] = lo.y; b[2] = hi.x; b[3] = hi.y;
        Bf[t][nt] = b;
      }

#pragma unroll
    for (int s = 0; s < 6; ++s) {
      v4i Af[2];
#pragma unroll
      for (int ot = 0; ot < 2; ++ot) {
        const char* ap = Wsl + (size_t)s * C_ * C_
                       + (size_t)(ob + wo + ot * 16 + lr) * C_ + cb + lg * 16;
        Af[ot] = *reinterpret_cast<const v4i*>(ap);
      }
#pragma unroll
      for (int t = 0; t < XS; ++t) {
        if (s + t <= 6) {
#pragma unroll
          for (int ot = 0; ot < 2; ++ot)
#pragma unroll
            for (int nt = 0; nt < 2; ++nt)
              acc[s + t][ot][nt] = __builtin_amdgcn_mfma_i32_16x16x64_i8(
                  Af[ot], Bf[t][nt], acc[s + t][ot][nt], 0, 0, 0);
        }
      }
    }
  }

  const double WGT[7] = {0x1p-10, 0x1p-18, 0x1p-26, 0x1p-34,
                         0x1p-42, 0x1p-50, 0x1p-58};
#pragma unroll
  for (int ot = 0; ot < 2; ++ot)
#pragma unroll
    for (int nt = 0; nt < 2; ++nt)
#pragma unroll
      for (int r = 0; r < 4; ++r) {
        double y = 0.0;
#pragma unroll
        for (int u = 0; u < NU; ++u)
          y = fma((double)acc[u][ot][nt][r], WGT[u], y);
        int o = ob + wo + ot * 16 + lg * 4 + r;
        int n = nb + wn + nt * 16 + lr;
        Y[((size_t)tb * C_ + o) * N_ + n] = y;
      }
}

__global__ __launch_bounds__(256) void attn_kernel(
    const u64* __restrict__ qb, const u64* __restrict__ kb,
    const u64* __restrict__ vb, float* __restrict__ A)
{
  __shared__ u64 kw[64][4], vw[64][4], qw[64][4];
  __shared__ int kvs[64][64];
  const int h  = blockIdx.x & 7;
  const int tb = blockIdx.x >> 3;
  const int tid = threadIdx.x;
  {
    int dd = tid >> 2, w = tid & 3;
    size_t base = ((size_t)tb * C_ + h * 64 + dd) * 4 + w;
    kw[dd][w] = kb[base];
    vw[dd][w] = vb[base];
    qw[dd][w] = qb[base];
  }
  __syncthreads();
  {
    int dd = tid >> 2;
    int e0 = (tid & 3) << 4;
    u64 k0 = kw[dd][0], k1 = kw[dd][1], k2 = kw[dd][2], k3 = kw[dd][3];
    for (int e = e0; e < e0 + 16; ++e) {
      int c = __popcll(k0 & vw[e][0]) + __popcll(k1 & vw[e][1])
            + __popcll(k2 & vw[e][2]) + __popcll(k3 & vw[e][3]);
      kvs[dd][e] = c;
    }
  }
  __syncthreads();
  const int n = tid;
  u64 qmask = 0;
  {
    int wsel = n >> 6, sh = n & 63;
#pragma unroll
    for (int dd = 0; dd < 64; ++dd)
      qmask |= ((qw[dd][wsel] >> sh) & 1ull) << dd;
  }
  float* Ap = A + ((size_t)tb * C_ + h * 64) * N_ + n;
  for (int e = 0; e < 64; ++e) {
    int s = 0;
#pragma unroll
    for (int dd = 0; dd < 64; ++dd) {
      int m = -(int)((qmask >> dd) & 1ull);
      s += kvs[dd][e] & m;
    }
    Ap[(size_t)e * N_] = (float)s * 0.125f;
  }
}

__global__ __launch_bounds__(256) void attn_lif(float* __restrict__ A)
{
  const size_t i = (size_t)blockIdx.x * 256 + threadIdx.x;
  const size_t stride = (size_t)B_ * C_ * N_;
  float v = 0.f;
#pragma unroll
  for (int t = 0; t < T_; ++t) {
    float a = A[t * stride + i];
    v = v + (a - v) * 0.5f;
    bool sp = (v >= 0.5f);
    A[t * stride + i] = sp ? 1.0f : 0.0f;
    if (sp) v = 0.f;
  }
}

__global__ __launch_bounds__(256) void bn_stats(
    const double* __restrict__ Y, double* __restrict__ stats)
{
  const int o = blockIdx.x;
  const int n = threadIdx.x;
  double s = 0.0, s2 = 0.0;
  for (int tb = 0; tb < TB_; ++tb) {
    double v = Y[((size_t)tb * C_ + o) * N_ + n];
    s += v;
    s2 = fma(v, v, s2);
  }
  __shared__ double rs[256], rq[256];
  rs[n] = s; rq[n] = s2;
  __syncthreads();
  for (int off = 128; off > 0; off >>= 1) {
    if (n < off) { rs[n] += rs[n + off]; rq[n] += rq[n + off]; }
    __syncthreads();
  }
  if (n == 0) {
    double mu  = rs[0] * (1.0 / 16384.0);
    double var = rq[0] * (1.0 / 16384.0) - mu * mu;
    stats[o]      = mu;
    stats[C_ + o] = 1.0 / sqrt(var + 1e-5);
  }
}

__global__ __launch_bounds__(256) void bn_lif_bits_fb(
    const double* __restrict__ Y, const double* __restrict__ stats,
    const float* __restrict__ gamma, const float* __restrict__ beta,
    double vth, u64* __restrict__ bits)
{
  const int o = blockIdx.x & (C_ - 1);
  const int b = blockIdx.x >> 9;
  const int n = threadIdx.x;
  const double mu = stats[o], rsig = stats[C_ + o];
  const double g = (double)gamma[o], be = (double)beta[o];
  double v = 0.0;
#pragma unroll
  for (int t = 0; t < T_; ++t) {
    double y  = Y[((size_t)(t * B_ + b) * C_ + o) * N_ + n];
    double yn = (y - mu) * rsig * g + be;
    v = v + (yn - v) * 0.5;
    bool sp = (v >= vth);
    u64 m = __ballot(sp);
    if ((n & 63) == 0)
      bits[((size_t)(t * B_ + b) * C_ + o) * (N_ / 64) + (n >> 6)] = m;
    if (sp) v = 0.0;
  }
}

__global__ __launch_bounds__(256) void bn_lif_out_fb(
    const double* __restrict__ Y, const double* __restrict__ stats,
    const float* __restrict__ gamma, const float* __restrict__ beta,
    float* __restrict__ out)
{
  const int o = blockIdx.x & (C_ - 1);
  const int b = blockIdx.x >> 9;
  const int n = threadIdx.x;
  const double mu = stats[o], rsig = stats[C_ + o];
  const double g = (double)gamma[o], be = (double)beta[o];
  double v = 0.0;
#pragma unroll
  for (int t = 0; t < T_; ++t) {
    double y  = Y[((size_t)(t * B_ + b) * C_ + o) * N_ + n];
    double yn = (y - mu) * rsig * g + be;
    v = v + (yn - v) * 0.5;
    bool sp = (v >= 1.0);
    out[((size_t)(t * B_ + b) * C_ + o) * N_ + n] = sp ? 1.0f : 0.0f;
    if (sp) v = 0.0;
  }
}

// ---------------------------------------------------------------------------
extern "C" void kernel_launch(void* const* d_in, const int* in_sizes, int n_in,
                              void* d_out, int out_size, void* d_ws, size_t ws_size,
                              hipStream_t stream)
{
  const float* x    = (const float*)d_in[0];
  const float* qW   = (const float*)d_in[1];
  const float* qg   = (const float*)d_in[2];
  const float* qbt  = (const float*)d_in[3];
  const float* kW   = (const float*)d_in[4];
  const float* kg   = (const float*)d_in[5];
  const float* kbt  = (const float*)d_in[6];
  const float* vW   = (const float*)d_in[7];
  const float* vg   = (const float*)d_in[8];
  const float* vbt  = (const float*)d_in[9];
  const float* pW   = (const float*)d_in[10];
  // d_in[11] proj_b cancels exactly under BN mean subtraction -> unused
  const float* pg   = (const float*)d_in[12];
  const float* pbt  = (const float*)d_in[13];

  char* ws = (char*)d_ws;
  double* yD    = (double*)ws;                    // 67,108,864 B
  u64*    bitsQ = (u64*)(ws + 100663296);         //  1,048,576 B
  u64*    bitsK = (u64*)(ws + 101711872);         //  1,048,576 B
  u64*    bitsV = (u64*)(ws + 102760448);         //  1,048,576 B
  u64*    istat = (u64*)(ws + 103809024);         //      8,192 B

  if (ws_size >= 105390080ull) {
    // ---------------- fast path: pre-digitized operand planes ----------------
    char*  Xd4  = ws + 67108864;                  // 33,554,432 B (dead after V)
    short* A16  = (short*)(ws + 67108864);        // 16,777,216 B (after V gemm)
    char*  Sp8  = ws + 67108864 + 16777216;       //  8,388,608 B
    char*  Wsl5 = ws + 103817216;                 //  1,310,720 B

    dim3 ggrid(4, 8, 64);

    predig_x<<<dim3(8, 4, 64), 256, 0, stream>>>(x, Xd4);
    // Q
    decomp_w5i<<<512, 128, 0, stream>>>(qW, Wsl5);
    hipMemsetAsync(istat, 0, 8192, stream);
    gemm_s<4><<<ggrid, 256, 0, stream>>>(Xd4, Wsl5, yD, istat);
    bn_lif_bits<<<8192, 256, 0, stream>>>(yD, istat, qg, qbt, 1.0, bitsQ);
    // K
    decomp_w5i<<<512, 128, 0, stream>>>(kW, Wsl5);
    hipMemsetAsync(istat, 0, 8192, stream);
    gemm_s<4><<<ggrid, 256, 0, stream>>>(Xd4, Wsl5, yD, istat);
    bn_lif_bits<<<8192, 256, 0, stream>>>(yD, istat, kg, kbt, 1.0, bitsK);
    // V
    decomp_w5i<<<512, 128, 0, stream>>>(vW, Wsl5);
    hipMemsetAsync(istat, 0, 8192, stream);
    gemm_s<4><<<ggrid, 256, 0, stream>>>(Xd4, Wsl5, yD, istat);
    bn_lif_bits<<<8192, 256, 0, stream>>>(yD, istat, vg, vbt, 1.0, bitsV);
    // attention (exact int) + LIF -> transposed binary i8 (overwrites Xd4)
    attn16<<<512, 256, 0, stream>>>(bitsQ, bitsK, bitsV, A16);
    attn_lif_sp<<<dim3(4, 8, 16), 256, 0, stream>>>(A16, Sp8);
    // projection (binary B, 5 w-digits)
    decomp_w5i<<<512, 128, 0, stream>>>(pW, Wsl5);
    hipMemsetAsync(istat, 0, 8192, stream);
    gemm_s<1><<<ggrid, 256, 0, stream>>>(Sp8, Wsl5, yD, istat);
    bn_lif_out<<<8192, 256, 0, stream>>>(yD, istat, pg, pbt, (float*)d_out);
  } else {
    // ---------------- fallback: proven R4 pipeline ----------------
    float*  A     = (float*)(ws + 67108864);
    char*   WslA  = ws + 67108864;
    char*   WslB  = ws + 100663296;
    double* stats = (double*)(ws + 103809024);

    dim3 ggrid(4, 8, 64);

    decomp_w<<<512, 128, 0, stream>>>(qW, WslA);
    gemm_i8<6><<<ggrid, 256, 0, stream>>>(x, WslA, yD);
    bn_stats<<<512, 256, 0, stream>>>(yD, stats);
    bn_lif_bits_fb<<<8192, 256, 0, stream>>>(yD, stats, qg, qbt, 1.0, bitsQ);
    decomp_w<<<512, 128, 0, stream>>>(kW, WslA);
    gemm_i8<6><<<ggrid, 256, 0, stream>>>(x, WslA, yD);
    bn_stats<<<512, 256, 0, stream>>>(yD, stats);
    bn_lif_bits_fb<<<8192, 256, 0, stream>>>(yD, stats, kg, kbt, 1.0, bitsK);
    decomp_w<<<512, 128, 0, stream>>>(vW, WslA);
    gemm_i8<6><<<ggrid, 256, 0, stream>>>(x, WslA, yD);
    bn_stats<<<512, 256, 0, stream>>>(yD, stats);
    bn_lif_bits_fb<<<8192, 256, 0, stream>>>(yD, stats, vg, vbt, 1.0, bitsV);
    attn_kernel<<<512, 256, 0, stream>>>(bitsQ, bitsK, bitsV, A);
    attn_lif<<<8192, 256, 0, stream>>>(A);
    decomp_w<<<512, 128, 0, stream>>>(pW, WslB);
    gemm_i8<1><<<ggrid, 256, 0, stream>>>(A, WslB, yD);
    bn_stats<<<512, 256, 0, stream>>>(yD, stats);
    bn_lif_out_fb<<<8192, 256, 0, stream>>>(yD, stats, pg, pbt, (float*)d_out);
  }
}